// Round 1
// baseline (7903.177 us; speedup 1.0000x reference)
//
#include <hip/hip_runtime.h>

#define L_ 256
#define B_ 256
#define V_ 50000
#define E_ 300
#define H_ 256
#define T_ 17
#define G4 1024  // 4*H

typedef short short8 __attribute__((ext_vector_type(8)));
typedef float f32x4 __attribute__((ext_vector_type(4)));

static __device__ __forceinline__ short f2bf(float x) {
    unsigned int u = __float_as_uint(x);
    u = (u + 0x7fffu + ((u >> 16) & 1u)) >> 16;   // RNE truncate to bf16
    return (short)u;
}
static __device__ __forceinline__ float bf2f(unsigned short u) {
    return __uint_as_float(((unsigned int)u) << 16);
}
static __device__ __forceinline__ float sigm(float x) { return 1.0f / (1.0f + __expf(-x)); }
static __device__ __forceinline__ float tanh_(float x) {
    float ax = fabsf(x);
    float e = __expf(2.0f * ax);
    float t = 1.0f - 2.0f / (e + 1.0f);
    return copysignf(t, x);
}

// ---------------------------------------------------------------------------
// Transpose + bf16-pack w_hh (4H x H, row-major) into k-major pair-packed
// layout: ushort index (k>>1)*2048 + g*2 + (k&1)  == uint32 index (k>>1)*1024+g
// holding (w[2k2][g], w[2k2+1][g]) in (lo,hi) halves.
// ---------------------------------------------------------------------------
__global__ __launch_bounds__(256) void prep_w(const float* __restrict__ wf,
                                              const float* __restrict__ wb,
                                              unsigned short* __restrict__ dstf,
                                              unsigned short* __restrict__ dstb) {
    int gid = blockIdx.x * 256 + threadIdx.x;      // 0 .. 2*262144-1
    int d = gid >> 18;
    int rem = gid & 262143;
    int k = rem >> 10;
    int g = rem & 1023;
    const float* src = d ? wb : wf;
    unsigned short* dst = d ? dstb : dstf;
    dst[(k >> 1) * 2048 + g * 2 + (k & 1)] = (unsigned short)f2bf(src[g * H_ + k]);
}

// ---------------------------------------------------------------------------
// tg[v][g] = sum_e table[v][e] * w_ih[g][e] + b_ih[g] + b_hh[g], stored bf16.
// MFMA 16x16x32 bf16. Block = 4 waves = 64 v-rows; wave tile = 16v x 128g.
// Grid: (ceil(50000/64)=782, 1024/128=8).
// ---------------------------------------------------------------------------
__global__ __launch_bounds__(256) void tg_gemm(const float* __restrict__ table,
                                               const float* __restrict__ w_ih,
                                               const float* __restrict__ b_ih,
                                               const float* __restrict__ b_hh,
                                               unsigned short* __restrict__ tg) {
    const int wave = threadIdx.x >> 6;
    const int lane = threadIdx.x & 63;
    const int v0 = blockIdx.x * 64 + wave * 16;
    if (v0 >= V_) return;                 // no __syncthreads in this kernel
    const int g0 = blockIdx.y * 128;
    const int m = lane & 15;              // A row / B col / D col
    const int q = lane >> 4;              // k-quad
    f32x4 acc[8];
#pragma unroll
    for (int gt = 0; gt < 8; ++gt) acc[gt] = (f32x4){0.f, 0.f, 0.f, 0.f};

    const float* arow = table + (size_t)(v0 + m) * E_;

    // full K tiles: e in [0, 288)
    for (int kt = 0; kt < 9; ++kt) {
        const int e0 = kt * 32 + q * 8;
        short8 af;
#pragma unroll
        for (int jj = 0; jj < 8; ++jj) af[jj] = f2bf(arow[e0 + jj]);
#pragma unroll
        for (int gt = 0; gt < 8; ++gt) {
            const float* brow = w_ih + (size_t)(g0 + gt * 16 + m) * E_;
            short8 bf;
#pragma unroll
            for (int jj = 0; jj < 8; ++jj) bf[jj] = f2bf(brow[e0 + jj]);
            acc[gt] = __builtin_amdgcn_mfma_f32_16x16x32_bf16(af, bf, acc[gt], 0, 0, 0);
        }
    }
    {   // tail tile: e in [288, 320) guarded to e < 300
        const int e0 = 288 + q * 8;
        short8 af;
#pragma unroll
        for (int jj = 0; jj < 8; ++jj) af[jj] = (e0 + jj < E_) ? f2bf(arow[e0 + jj]) : (short)0;
#pragma unroll
        for (int gt = 0; gt < 8; ++gt) {
            const float* brow = w_ih + (size_t)(g0 + gt * 16 + m) * E_;
            short8 bf;
#pragma unroll
            for (int jj = 0; jj < 8; ++jj) bf[jj] = (e0 + jj < E_) ? f2bf(brow[e0 + jj]) : (short)0;
            acc[gt] = __builtin_amdgcn_mfma_f32_16x16x32_bf16(af, bf, acc[gt], 0, 0, 0);
        }
    }
    // epilogue: D col = lane&15, row = (lane>>4)*4 + r  [guide §3, m89-verified]
#pragma unroll
    for (int gt = 0; gt < 8; ++gt) {
        const int g = g0 + gt * 16 + m;
        const float bias = b_ih[g] + b_hh[g];
#pragma unroll
        for (int r = 0; r < 4; ++r) {
            const int v = v0 + q * 4 + r;
            tg[(size_t)v * G4 + g] = (unsigned short)f2bf(acc[gt][r] + bias);
        }
    }
}

// ---------------------------------------------------------------------------
// LSTM over 256 steps, one launch per direction. Block = 2 batch elems x 256 j,
// 512 threads. h double-buffered in LDS, c in registers. w_hh^T bf16 packed.
// Emissions (T=17) reduced per step: forward writes lin_b + h_f . W[:, :256],
// backward accumulates h_b . W[:, 256:].
// ---------------------------------------------------------------------------
__global__ __launch_bounds__(512) void lstm_kernel(const unsigned short* __restrict__ tg,
                                                   const unsigned int* __restrict__ wT,
                                                   const int* __restrict__ words,
                                                   const float* __restrict__ lin_w,
                                                   const float* __restrict__ lin_b,
                                                   float* __restrict__ em,
                                                   int forward) {
    __shared__ __align__(16) float hrow[2][2][H_];
    const int tid = threadIdx.x;
    const int b_loc = tid >> 8;
    const int j = tid & 255;
    const int b = blockIdx.x * 2 + b_loc;

    float c = 0.0f;
    hrow[0][b_loc][j] = 0.0f;
    __syncthreads();

    const int wv = tid >> 6;
    const int b2 = wv >> 2;        // which batch elem this wave reduces emissions for
    const int quad = wv & 3;       // which t-residue class
    const int lane = tid & 63;
    const int off = forward ? 0 : H_;

    int p = 0;
    for (int step = 0; step < L_; ++step) {
        const int l = forward ? step : (L_ - 1 - step);
        const int word = words[l * B_ + b];
        const unsigned short* tgrow = tg + (size_t)word * G4;
        float a0 = bf2f(tgrow[j]);
        float a1 = bf2f(tgrow[256 + j]);
        float a2 = bf2f(tgrow[512 + j]);
        float a3 = bf2f(tgrow[768 + j]);

        const float2* hr2 = (const float2*)hrow[p][b_loc];
#pragma unroll 8
        for (int k2 = 0; k2 < 128; ++k2) {
            float2 h2 = hr2[k2];
            unsigned int u0 = wT[k2 * 1024 + j];
            unsigned int u1 = wT[k2 * 1024 + 256 + j];
            unsigned int u2 = wT[k2 * 1024 + 512 + j];
            unsigned int u3 = wT[k2 * 1024 + 768 + j];
            a0 += h2.x * __uint_as_float(u0 << 16) + h2.y * __uint_as_float(u0 & 0xffff0000u);
            a1 += h2.x * __uint_as_float(u1 << 16) + h2.y * __uint_as_float(u1 & 0xffff0000u);
            a2 += h2.x * __uint_as_float(u2 << 16) + h2.y * __uint_as_float(u2 & 0xffff0000u);
            a3 += h2.x * __uint_as_float(u3 << 16) + h2.y * __uint_as_float(u3 & 0xffff0000u);
        }
        const float ig = sigm(a0);
        const float fg = sigm(a1);
        const float gg = tanh_(a2);
        const float og = sigm(a3);
        c = fg * c + ig * gg;
        const float h = og * tanh_(c);
        hrow[p ^ 1][b_loc][j] = h;
        __syncthreads();

        // emissions: wave (b2, quad) handles t = quad, quad+4, ...
        const float4 hv = ((const float4*)hrow[p ^ 1][b2])[lane];
        for (int t = quad; t < T_; t += 4) {
            const float4 w4 = *(const float4*)(lin_w + t * (2 * H_) + off + lane * 4);
            float s = hv.x * w4.x + hv.y * w4.y + hv.z * w4.z + hv.w * w4.w;
            for (int o = 32; o; o >>= 1) s += __shfl_down(s, o);
            if (lane == 0) {
                float* ep = em + ((size_t)l * B_ + (blockIdx.x * 2 + b2)) * T_ + t;
                if (forward) *ep = lin_b[t] + s;
                else *ep += s;
            }
        }
        p ^= 1;
        __syncthreads();
    }
}

// ---------------------------------------------------------------------------
// CRF: one 64-thread wave per sequence. Lanes t<17 hold alpha; 17-wide
// shfl logsumexp per step. Numerator score lane-parallel over l.
// ---------------------------------------------------------------------------
__global__ __launch_bounds__(64) void crf_kernel(const float* __restrict__ em,
                                                 const int* __restrict__ tags,
                                                 const int* __restrict__ mask,
                                                 const float* __restrict__ start_trans,
                                                 const float* __restrict__ end_trans,
                                                 const float* __restrict__ trans,
                                                 float* __restrict__ llh) {
    const int b = blockIdx.x;
    const int t = threadIdx.x;
    __shared__ float tr[T_ * T_];
    for (int i = t; i < T_ * T_; i += 64) tr[i] = trans[i];
    __syncthreads();

    // ---- numerator score ----
    float part = 0.0f;
    int msum = 0;
    for (int l = t; l < L_; l += 64) {
        const int idx = l * B_ + b;
        const int m = mask[idx];
        msum += m;
        const int tl = tags[idx];
        const float emt = em[(size_t)idx * T_ + tl];
        if (l == 0) {
            part += start_trans[tl] + emt;
        } else {
            const int tp = tags[(l - 1) * B_ + b];
            part += m ? (tr[tp * T_ + tl] + emt) : 0.0f;
        }
    }
    for (int o = 32; o; o >>= 1) {
        part += __shfl_down(part, o);
        msum += __shfl_down(msum, o);
    }

    // ---- logZ forward algorithm ----
    const int tc = (t < T_) ? t : (T_ - 1);
    float alpha = start_trans[tc] + em[(size_t)b * T_ + tc];
    for (int l = 1; l < L_; ++l) {
        if (mask[l * B_ + b] == 0) break;   // mask monotone within a sequence
        const float emt = em[((size_t)l * B_ + b) * T_ + tc];
        float mx = -1e30f;
#pragma unroll
        for (int s = 0; s < T_; ++s) {
            const float as = __shfl(alpha, s);
            mx = fmaxf(mx, as + tr[s * T_ + tc]);
        }
        float sm = 0.0f;
#pragma unroll
        for (int s = 0; s < T_; ++s) {
            const float as = __shfl(alpha, s);
            sm += __expf(as + tr[s * T_ + tc] - mx);
        }
        alpha = mx + __logf(sm) + emt;
    }
    float val = (t < T_) ? (alpha + end_trans[t]) : -1e30f;
    float mx = val;
    for (int o = 32; o; o >>= 1) mx = fmaxf(mx, __shfl_down(mx, o));
    const float mx_all = __shfl(mx, 0);
    float sm = __expf(val - mx_all);
    for (int o = 32; o; o >>= 1) sm += __shfl_down(sm, o);

    if (t == 0) {
        const float score = part + end_trans[tags[(msum - 1) * B_ + b]];
        const float logZ = mx_all + __logf(sm);
        llh[b] = score - logZ;
    }
}

__global__ __launch_bounds__(256) void final_reduce(const float* __restrict__ llh,
                                                    float* __restrict__ out) {
    const int t = threadIdx.x;
    float v = llh[t];
    for (int o = 32; o; o >>= 1) v += __shfl_down(v, o);
    __shared__ float wsum[4];
    if ((t & 63) == 0) wsum[t >> 6] = v;
    __syncthreads();
    if (t == 0) out[0] = -(wsum[0] + wsum[1] + wsum[2] + wsum[3]);
}

// ---------------------------------------------------------------------------
extern "C" void kernel_launch(void* const* d_in, const int* in_sizes, int n_in,
                              void* d_out, int out_size, void* d_ws, size_t ws_size,
                              hipStream_t stream) {
    const int* words = (const int*)d_in[0];
    const int* tags = (const int*)d_in[1];
    const int* mask = (const int*)d_in[2];
    const float* table = (const float*)d_in[3];
    const float* w_ih_f = (const float*)d_in[4];
    const float* w_hh_f = (const float*)d_in[5];
    const float* b_ih_f = (const float*)d_in[6];
    const float* b_hh_f = (const float*)d_in[7];
    const float* w_ih_b = (const float*)d_in[8];
    const float* w_hh_b = (const float*)d_in[9];
    const float* b_ih_b = (const float*)d_in[10];
    const float* b_hh_b = (const float*)d_in[11];
    const float* lin_w = (const float*)d_in[12];
    const float* lin_b = (const float*)d_in[13];
    const float* start_trans = (const float*)d_in[14];
    const float* end_trans = (const float*)d_in[15];
    const float* trans = (const float*)d_in[16];

    char* ws = (char*)d_ws;
    unsigned short* tg = (unsigned short*)ws;                  // 102,400,000 B
    unsigned short* wTf = (unsigned short*)(ws + 102400000);   //     524,288 B
    unsigned short* wTb = (unsigned short*)(ws + 102924288);   //     524,288 B
    float* em = (float*)(ws + 103448576);                      //   4,456,448 B
    float* llh = (float*)(ws + 107905024);                     //       1,024 B
    // total ws use: 107,906,048 B

    prep_w<<<2048, 256, 0, stream>>>(w_hh_f, w_hh_b, wTf, wTb);

    // forward direction
    tg_gemm<<<dim3(782, 8), 256, 0, stream>>>(table, w_ih_f, b_ih_f, b_hh_f, tg);
    lstm_kernel<<<128, 512, 0, stream>>>(tg, (const unsigned int*)wTf, words, lin_w, lin_b, em, 1);

    // backward direction (reuses tg buffer; stream order serializes)
    tg_gemm<<<dim3(782, 8), 256, 0, stream>>>(table, w_ih_b, b_ih_b, b_hh_b, tg);
    lstm_kernel<<<128, 512, 0, stream>>>(tg, (const unsigned int*)wTb, words, lin_w, lin_b, em, 0);

    crf_kernel<<<256, 64, 0, stream>>>(em, tags, mask, start_trans, end_trans, trans, llh);
    final_reduce<<<1, 256, 0, stream>>>(llh, (float*)d_out);
}

// Round 2
// 6053.838 us; speedup vs baseline: 1.3055x; 1.3055x over previous
//
#include <hip/hip_runtime.h>

#define L_ 256
#define B_ 256
#define V_ 50000
#define E_ 300
#define H_ 256
#define T_ 17
#define G4 1024  // 4*H

typedef short short8 __attribute__((ext_vector_type(8)));
typedef float f32x4 __attribute__((ext_vector_type(4)));

static __device__ __forceinline__ short f2bf(float x) {
    unsigned int u = __float_as_uint(x);
    u = (u + 0x7fffu + ((u >> 16) & 1u)) >> 16;   // RNE truncate to bf16
    return (short)u;
}
static __device__ __forceinline__ float bf2f(unsigned short u) {
    return __uint_as_float(((unsigned int)u) << 16);
}
static __device__ __forceinline__ float sigm(float x) { return 1.0f / (1.0f + __expf(-x)); }
static __device__ __forceinline__ float tanh_(float x) {
    float ax = fabsf(x);
    float e = __expf(2.0f * ax);
    float t = 1.0f - 2.0f / (e + 1.0f);
    return copysignf(t, x);
}

// ---------------------------------------------------------------------------
// prep_all: pack w_hh (both dirs) into MFMA B-fragment order, and lin_w into
// per-direction B-fragment order for the fused emission MFMA.
// wB flat ushort idx = dir*262144 + wv*32768 + kt*4096 + fr*512 + lane*8 + jj
//   fr = gt*2+jt;  g = gt*256 + wv*32 + jt*16 + (lane&15);  k = kt*32+(lane>>4)*8+jj
// linB flat ushort idx = dir*8192 + nt*4096 + kt*512 + lane*8 + jj
//   t = nt*16+(lane&15) (0 if >=17); k = kt*32+(lane>>4)*8+jj; val = lin_w[t][dir*256+k]
// ---------------------------------------------------------------------------
__global__ __launch_bounds__(256) void prep_all(const float* __restrict__ whf,
                                                const float* __restrict__ whb,
                                                const float* __restrict__ lin_w,
                                                unsigned short* __restrict__ wB,
                                                unsigned short* __restrict__ linB) {
    int gid = blockIdx.x * 256 + threadIdx.x;
    if (gid < 524288) {
        int dir = gid >> 18;
        int t = gid & 262143;
        int jj = t & 7;
        int lane = (t >> 3) & 63;
        int fr = (t >> 9) & 7;
        int kt = (t >> 12) & 7;
        int wv = t >> 15;
        int gt = fr >> 1, jt = fr & 1;
        int g = gt * 256 + wv * 32 + jt * 16 + (lane & 15);
        int k = kt * 32 + (lane >> 4) * 8 + jj;
        const float* w = dir ? whb : whf;
        wB[gid] = (unsigned short)f2bf(w[g * H_ + k]);
    } else if (gid < 524288 + 16384) {
        int i = gid - 524288;
        int jj = i & 7;
        int lane = (i >> 3) & 63;
        int kt = (i >> 9) & 7;
        int nt = (i >> 12) & 1;
        int dir = (i >> 13) & 1;
        int t = nt * 16 + (lane & 15);
        int k = kt * 32 + (lane >> 4) * 8 + jj;
        float v = (t < T_) ? lin_w[t * (2 * H_) + dir * H_ + k] : 0.0f;
        linB[i] = (unsigned short)f2bf(v);
    }
}

// ---------------------------------------------------------------------------
// tg[v][g] = sum_e table[v][e] * w_ih[g][e] + b_ih[g] + b_hh[g], stored bf16.
// (unchanged from round 1 — verified correct)
// ---------------------------------------------------------------------------
__global__ __launch_bounds__(256) void tg_gemm(const float* __restrict__ table,
                                               const float* __restrict__ w_ih,
                                               const float* __restrict__ b_ih,
                                               const float* __restrict__ b_hh,
                                               unsigned short* __restrict__ tg) {
    const int wave = threadIdx.x >> 6;
    const int lane = threadIdx.x & 63;
    const int v0 = blockIdx.x * 64 + wave * 16;
    if (v0 >= V_) return;
    const int g0 = blockIdx.y * 128;
    const int m = lane & 15;
    const int q = lane >> 4;
    f32x4 acc[8];
#pragma unroll
    for (int gt = 0; gt < 8; ++gt) acc[gt] = (f32x4){0.f, 0.f, 0.f, 0.f};

    const float* arow = table + (size_t)(v0 + m) * E_;

    for (int kt = 0; kt < 9; ++kt) {
        const int e0 = kt * 32 + q * 8;
        short8 af;
#pragma unroll
        for (int jj = 0; jj < 8; ++jj) af[jj] = f2bf(arow[e0 + jj]);
#pragma unroll
        for (int gt = 0; gt < 8; ++gt) {
            const float* brow = w_ih + (size_t)(g0 + gt * 16 + m) * E_;
            short8 bf;
#pragma unroll
            for (int jj = 0; jj < 8; ++jj) bf[jj] = f2bf(brow[e0 + jj]);
            acc[gt] = __builtin_amdgcn_mfma_f32_16x16x32_bf16(af, bf, acc[gt], 0, 0, 0);
        }
    }
    {
        const int e0 = 288 + q * 8;
        short8 af;
#pragma unroll
        for (int jj = 0; jj < 8; ++jj) af[jj] = (e0 + jj < E_) ? f2bf(arow[e0 + jj]) : (short)0;
#pragma unroll
        for (int gt = 0; gt < 8; ++gt) {
            const float* brow = w_ih + (size_t)(g0 + gt * 16 + m) * E_;
            short8 bf;
#pragma unroll
            for (int jj = 0; jj < 8; ++jj) bf[jj] = (e0 + jj < E_) ? f2bf(brow[e0 + jj]) : (short)0;
            acc[gt] = __builtin_amdgcn_mfma_f32_16x16x32_bf16(af, bf, acc[gt], 0, 0, 0);
        }
    }
#pragma unroll
    for (int gt = 0; gt < 8; ++gt) {
        const int g = g0 + gt * 16 + m;
        const float bias = b_ih[g] + b_hh[g];
#pragma unroll
        for (int r = 0; r < 4; ++r) {
            const int v = v0 + q * 4 + r;
            tg[(size_t)v * G4 + g] = (unsigned short)f2bf(acc[gt][r] + bias);
        }
    }
}

// ---------------------------------------------------------------------------
// MFMA LSTM: 16 blocks x 512 thr. Block owns 16 batches. Per step:
// gates(16x1024) = h(16x256) @ wT + tg  via 16x16x32 bf16 MFMA.
// Wave wv owns gate cols {gt*256 + wv*32 + jt*16 + n}: i,f,g,o for j in
// [wv*32, wv*32+32) all in-wave -> no cross-wave exchange, 1 barrier/step.
// wT streamed from L2 as pre-packed B-frags (dwordx4, double-buffered).
// h in LDS bf16 (A-frag layout), c in regs. Emissions fused: waves 0,1 do a
// 16x32x256 MFMA per step vs pre-packed lin_w frags.
// ---------------------------------------------------------------------------
__global__ __launch_bounds__(512) void lstm_mfma(const unsigned short* __restrict__ tg,
                                                 const uint4* __restrict__ wB,
                                                 const int* __restrict__ words,
                                                 const unsigned short* __restrict__ linB,
                                                 const float* __restrict__ lin_b,
                                                 float* __restrict__ em,
                                                 int dir) {
    __shared__ __align__(16) unsigned short hbuf[2][16][264];  // padded 256->264
    const int tid = threadIdx.x;
    const int wv = tid >> 6;
    const int lane = tid & 63;
    const int n = lane & 15;
    const int q = lane >> 4;
    const int b0 = blockIdx.x * 16;

    for (int i = tid; i < 16 * 264; i += 512) (&hbuf[0][0][0])[i] = 0;
    __syncthreads();

    float cst[2][4];
#pragma unroll
    for (int jt = 0; jt < 2; ++jt)
#pragma unroll
        for (int r = 0; r < 4; ++r) cst[jt][r] = 0.0f;

    const int l0 = dir ? (L_ - 1) : 0;
    const int dl = dir ? -1 : 1;

    // gate-column offsets for this lane: g = gt*256 + wv*32 + jt*16 + n
    int gcol[4][2];
#pragma unroll
    for (int gt = 0; gt < 4; ++gt)
#pragma unroll
        for (int jt = 0; jt < 2; ++jt) gcol[gt][jt] = gt * 256 + wv * 32 + jt * 16 + n;

    // preamble: words + tg for step 0 (stall once), words for step 1
    int wnxt[4];
    float tgc[4][2][4];
    {
        int wcur[4];
#pragma unroll
        for (int r = 0; r < 4; ++r) wcur[r] = words[l0 * B_ + b0 + q * 4 + r];
#pragma unroll
        for (int gt = 0; gt < 4; ++gt)
#pragma unroll
            for (int jt = 0; jt < 2; ++jt)
#pragma unroll
                for (int r = 0; r < 4; ++r)
                    tgc[gt][jt][r] = bf2f(tg[(size_t)wcur[r] * G4 + gcol[gt][jt]]);
#pragma unroll
        for (int r = 0; r < 4; ++r) wnxt[r] = words[(l0 + dl) * B_ + b0 + q * 4 + r];
    }

    const uint4* wBw = wB + (size_t)wv * 4096;  // this wave's frags: [kt][fr][lane]
    const unsigned short* lbfrag = linB + ((size_t)(dir * 2 + wv)) * 4096;
    float lbv = 0.0f;
    const int t_em = wv * 16 + n;
    if (wv < 2 && t_em < T_) lbv = lin_b[t_em];

    uint4 bfr[2][8];
#pragma unroll
    for (int fr = 0; fr < 8; ++fr) bfr[0][fr] = wBw[fr * 64 + lane];

    int p = 0;
    for (int step = 0; step < L_; ++step) {
        const int l = l0 + dl * step;
        f32x4 acc[4][2];
#pragma unroll
        for (int gt = 0; gt < 4; ++gt)
#pragma unroll
            for (int jt = 0; jt < 2; ++jt)
                acc[gt][jt] = (f32x4){tgc[gt][jt][0], tgc[gt][jt][1], tgc[gt][jt][2], tgc[gt][jt][3]};

        // prefetch next step's tg and step+2's words (overlaps the kt loop)
        float tgn[4][2][4] = {};
        int wtmp[4] = {0, 0, 0, 0};
        if (step + 1 < L_) {
#pragma unroll
            for (int gt = 0; gt < 4; ++gt)
#pragma unroll
                for (int jt = 0; jt < 2; ++jt)
#pragma unroll
                    for (int r = 0; r < 4; ++r)
                        tgn[gt][jt][r] = bf2f(tg[(size_t)wnxt[r] * G4 + gcol[gt][jt]]);
        }
        if (step + 2 < L_) {
            const int lnn = l + 2 * dl;
#pragma unroll
            for (int r = 0; r < 4; ++r) wtmp[r] = words[lnn * B_ + b0 + q * 4 + r];
        }

#pragma unroll
        for (int kt = 0; kt < 8; ++kt) {
            const int cur = kt & 1;
            if (kt < 7) {
#pragma unroll
                for (int fr = 0; fr < 8; ++fr) bfr[cur ^ 1][fr] = wBw[((kt + 1) * 8 + fr) * 64 + lane];
            }
            const short8 af = *(const short8*)&hbuf[p][n][kt * 32 + q * 8];
#pragma unroll
            for (int gt = 0; gt < 4; ++gt)
#pragma unroll
                for (int jt = 0; jt < 2; ++jt) {
                    const short8 bf = *(const short8*)&bfr[cur][gt * 2 + jt];
                    acc[gt][jt] = __builtin_amdgcn_mfma_f32_16x16x32_bf16(af, bf, acc[gt][jt], 0, 0, 0);
                }
        }

        // gate nonlinearities + h write (lane owns batches q*4+r, cols wv*32+jt*16+n)
#pragma unroll
        for (int jt = 0; jt < 2; ++jt)
#pragma unroll
            for (int r = 0; r < 4; ++r) {
                const float ig = sigm(acc[0][jt][r]);
                const float fg = sigm(acc[1][jt][r]);
                const float gg = tanh_(acc[2][jt][r]);
                const float og = sigm(acc[3][jt][r]);
                const float cn = fg * cst[jt][r] + ig * gg;
                cst[jt][r] = cn;
                const float h = og * tanh_(cn);
                hbuf[p ^ 1][q * 4 + r][wv * 32 + jt * 16 + n] = (unsigned short)f2bf(h);
            }

        // prefetch next step's kt=0 B-frags (bfr[0] free after kt=6)
#pragma unroll
        for (int fr = 0; fr < 8; ++fr) bfr[0][fr] = wBw[fr * 64 + lane];

        __syncthreads();

        // fused emissions on waves 0,1: em[l,b][t] (+)= h . lin_w_dir[t]
        if (wv < 2) {
            f32x4 eacc = (f32x4){0.f, 0.f, 0.f, 0.f};
#pragma unroll
            for (int kt = 0; kt < 8; ++kt) {
                const short8 af = *(const short8*)&hbuf[p ^ 1][n][kt * 32 + q * 8];
                const short8 bf = *(const short8*)&lbfrag[kt * 512 + lane * 8];
                eacc = __builtin_amdgcn_mfma_f32_16x16x32_bf16(af, bf, eacc, 0, 0, 0);
            }
            if (t_em < T_) {
#pragma unroll
                for (int r = 0; r < 4; ++r) {
                    float* ep = em + ((size_t)l * B_ + b0 + q * 4 + r) * T_ + t_em;
                    if (dir == 0) *ep = eacc[r] + lbv;
                    else *ep += eacc[r];
                }
            }
        }

        // rotate prefetched state
#pragma unroll
        for (int gt = 0; gt < 4; ++gt)
#pragma unroll
            for (int jt = 0; jt < 2; ++jt)
#pragma unroll
                for (int r = 0; r < 4; ++r) tgc[gt][jt][r] = tgn[gt][jt][r];
#pragma unroll
        for (int r = 0; r < 4; ++r) wnxt[r] = wtmp[r];
        p ^= 1;
    }
}

// ---------------------------------------------------------------------------
// CRF: one 64-thread wave per sequence. (unchanged from round 1)
// ---------------------------------------------------------------------------
__global__ __launch_bounds__(64) void crf_kernel(const float* __restrict__ em,
                                                 const int* __restrict__ tags,
                                                 const int* __restrict__ mask,
                                                 const float* __restrict__ start_trans,
                                                 const float* __restrict__ end_trans,
                                                 const float* __restrict__ trans,
                                                 float* __restrict__ llh) {
    const int b = blockIdx.x;
    const int t = threadIdx.x;
    __shared__ float tr[T_ * T_];
    for (int i = t; i < T_ * T_; i += 64) tr[i] = trans[i];
    __syncthreads();

    float part = 0.0f;
    int msum = 0;
    for (int l = t; l < L_; l += 64) {
        const int idx = l * B_ + b;
        const int m = mask[idx];
        msum += m;
        const int tl = tags[idx];
        const float emt = em[(size_t)idx * T_ + tl];
        if (l == 0) {
            part += start_trans[tl] + emt;
        } else {
            const int tp = tags[(l - 1) * B_ + b];
            part += m ? (tr[tp * T_ + tl] + emt) : 0.0f;
        }
    }
    for (int o = 32; o; o >>= 1) {
        part += __shfl_down(part, o);
        msum += __shfl_down(msum, o);
    }

    const int tc = (t < T_) ? t : (T_ - 1);
    float alpha = start_trans[tc] + em[(size_t)b * T_ + tc];
    for (int l = 1; l < L_; ++l) {
        if (mask[l * B_ + b] == 0) break;
        const float emt = em[((size_t)l * B_ + b) * T_ + tc];
        float mx = -1e30f;
#pragma unroll
        for (int s = 0; s < T_; ++s) {
            const float as = __shfl(alpha, s);
            mx = fmaxf(mx, as + tr[s * T_ + tc]);
        }
        float sm = 0.0f;
#pragma unroll
        for (int s = 0; s < T_; ++s) {
            const float as = __shfl(alpha, s);
            sm += __expf(as + tr[s * T_ + tc] - mx);
        }
        alpha = mx + __logf(sm) + emt;
    }
    float val = (t < T_) ? (alpha + end_trans[t]) : -1e30f;
    float mx = val;
    for (int o = 32; o; o >>= 1) mx = fmaxf(mx, __shfl_down(mx, o));
    const float mx_all = __shfl(mx, 0);
    float sm = __expf(val - mx_all);
    for (int o = 32; o; o >>= 1) sm += __shfl_down(sm, o);

    if (t == 0) {
        const float score = part + end_trans[tags[(msum - 1) * B_ + b]];
        const float logZ = mx_all + __logf(sm);
        llh[b] = score - logZ;
    }
}

__global__ __launch_bounds__(256) void final_reduce(const float* __restrict__ llh,
                                                    float* __restrict__ out) {
    const int t = threadIdx.x;
    float v = llh[t];
    for (int o = 32; o; o >>= 1) v += __shfl_down(v, o);
    __shared__ float wsum[4];
    if ((t & 63) == 0) wsum[t >> 6] = v;
    __syncthreads();
    if (t == 0) out[0] = -(wsum[0] + wsum[1] + wsum[2] + wsum[3]);
}

// ---------------------------------------------------------------------------
extern "C" void kernel_launch(void* const* d_in, const int* in_sizes, int n_in,
                              void* d_out, int out_size, void* d_ws, size_t ws_size,
                              hipStream_t stream) {
    const int* words = (const int*)d_in[0];
    const int* tags = (const int*)d_in[1];
    const int* mask = (const int*)d_in[2];
    const float* table = (const float*)d_in[3];
    const float* w_ih_f = (const float*)d_in[4];
    const float* w_hh_f = (const float*)d_in[5];
    const float* b_ih_f = (const float*)d_in[6];
    const float* b_hh_f = (const float*)d_in[7];
    const float* w_ih_b = (const float*)d_in[8];
    const float* w_hh_b = (const float*)d_in[9];
    const float* b_ih_b = (const float*)d_in[10];
    const float* b_hh_b = (const float*)d_in[11];
    const float* lin_w = (const float*)d_in[12];
    const float* lin_b = (const float*)d_in[13];
    const float* start_trans = (const float*)d_in[14];
    const float* end_trans = (const float*)d_in[15];
    const float* trans = (const float*)d_in[16];

    char* ws = (char*)d_ws;
    unsigned short* tg = (unsigned short*)ws;                 // 102,400,000 B
    unsigned short* wB = (unsigned short*)(ws + 102400000);   //  1,048,576 B
    unsigned short* linB = (unsigned short*)(ws + 103448576); //     32,768 B
    float* em = (float*)(ws + 103481344);                     //  4,456,448 B
    float* llh = (float*)(ws + 107937792);                    //      1,024 B
    // total ws use: 107,938,816 B

    prep_all<<<2112, 256, 0, stream>>>(w_hh_f, w_hh_b, lin_w, wB, linB);

    // forward direction
    tg_gemm<<<dim3(782, 8), 256, 0, stream>>>(table, w_ih_f, b_ih_f, b_hh_f, tg);
    lstm_mfma<<<16, 512, 0, stream>>>(tg, (const uint4*)wB, words, linB, lin_b, em, 0);

    // backward direction (reuses tg; stream order serializes)
    tg_gemm<<<dim3(782, 8), 256, 0, stream>>>(table, w_ih_b, b_ih_b, b_hh_b, tg);
    lstm_mfma<<<16, 512, 0, stream>>>(tg, (const uint4*)(wB + 262144), words, linB, lin_b, em, 1);

    crf_kernel<<<256, 64, 0, stream>>>(em, tags, mask, start_trans, end_trans, trans, llh);
    final_reduce<<<1, 256, 0, stream>>>(llh, (float*)d_out);
}

// Round 3
// 3389.028 us; speedup vs baseline: 2.3320x; 1.7863x over previous
//
#include <hip/hip_runtime.h>

#define L_ 256
#define B_ 256
#define V_ 50000
#define E_ 300
#define H_ 256
#define T_ 17
#define G4 1024  // 4*H

typedef short short8 __attribute__((ext_vector_type(8)));
typedef float f32x4 __attribute__((ext_vector_type(4)));

static __device__ __forceinline__ short f2bf(float x) {
    unsigned int u = __float_as_uint(x);
    u = (u + 0x7fffu + ((u >> 16) & 1u)) >> 16;   // RNE to bf16
    return (short)u;
}
static __device__ __forceinline__ float bf2f(unsigned int u) {
    return __uint_as_float(u << 16);
}
// f32 -> OCP e4m3fn, RNE, input must be finite; clamps to +-448.
static __device__ __forceinline__ unsigned int f2fp8(float x) {
    float ax = fminf(fabsf(x), 448.0f);
    int e = (int)(__float_as_uint(ax) >> 23) - 127;     // ax==0 -> -127
    int ec = e < -6 ? -6 : e;
    float sc = __uint_as_float((unsigned int)(130 - ec) << 23);  // 2^(3-ec)
    float t = __builtin_fmaf(ax, sc, 12582912.0f);               // + (2^23+2^22): RNE int in low bits
    int n = (int)(__float_as_uint(t) & 0x3fffff);                // n in [0,16]
    int code = ((ec + 7) << 3) + n - 8;                          // n==16 rolls to next exponent
    return (unsigned int)code | ((__float_as_uint(x) >> 24) & 0x80);
}
static __device__ __forceinline__ float sigm(float x) { return 1.0f / (1.0f + __expf(-x)); }
static __device__ __forceinline__ float tanh_(float x) {
    float ax = fabsf(x);
    float e = __expf(2.0f * ax);
    float t = 1.0f - 2.0f / (e + 1.0f);
    return copysignf(t, x);
}

// ---------------------------------------------------------------------------
// prep_all: pack w_hh (both dirs, scaled x64) into fp8 MFMA B-frag order, and
// lin_w (scaled x32) into fp8 B-frag order for the fused emission MFMA.
// wB8 byte = dir*262144 + wv*32768 + i*1024 + lane*16 + fo*8 + j
//   (i = kt*4+fp; gt=fp; jt=fo; g = gt*256+wv*32+jt*16+(lane&15); k = kt*32+(lane>>4)*8+j)
// linB8 byte = (dir*2+wv)*4096 + kt*512 + lane*8 + j
//   (t = wv*16+(lane&15), 0 if >=17; k = kt*32+(lane>>4)*8+j)
// ---------------------------------------------------------------------------
__global__ __launch_bounds__(256) void prep_all(const float* __restrict__ whf,
                                                const float* __restrict__ whb,
                                                const float* __restrict__ lin_w,
                                                unsigned char* __restrict__ wB8,
                                                unsigned char* __restrict__ linB8) {
    int gid = blockIdx.x * 256 + threadIdx.x;
    if (gid < 524288) {
        int dir = gid >> 18;
        int t = gid & 262143;
        int wv = t >> 15;
        int i = (t >> 10) & 31;
        int lane = (t >> 4) & 63;
        int fo = (t >> 3) & 1;
        int j = t & 7;
        int kt = i >> 2, fp = i & 3;
        int g = fp * 256 + wv * 32 + fo * 16 + (lane & 15);
        int k = kt * 32 + (lane >> 4) * 8 + j;
        const float* w = dir ? whb : whf;
        wB8[gid] = (unsigned char)f2fp8(w[g * H_ + k] * 64.0f);
    } else {
        int i2 = gid - 524288;  // < 16384
        int dir = (i2 >> 13) & 1;
        int wv = (i2 >> 12) & 1;
        int kt = (i2 >> 9) & 7;
        int lane = (i2 >> 3) & 63;
        int j = i2 & 7;
        int t = wv * 16 + (lane & 15);
        int k = kt * 32 + (lane >> 4) * 8 + j;
        float v = (t < T_) ? lin_w[t * (2 * H_) + dir * H_ + k] * 32.0f : 0.0f;
        linB8[i2] = (unsigned char)f2fp8(v);
    }
}

// ---------------------------------------------------------------------------
// tg[v][g] = 512*(sum_e table[v][e]*w_ih[g][e] + b_ih[g] + b_hh[g]), bf16.
// (x512 pre-scale so the fp8 LSTM MFMA, whose products carry x512, can
// accumulate directly onto it.)
// Block: 512 thr = 8 waves, 128 v-rows x 128 g-cols. B staged in LDS as bf16.
// Grid: (ceil(50048/128)=391, 8).
// ---------------------------------------------------------------------------
__global__ __launch_bounds__(512) void tg_gemm(const float* __restrict__ table,
                                               const float* __restrict__ w_ih,
                                               const float* __restrict__ b_ih,
                                               const float* __restrict__ b_hh,
                                               unsigned short* __restrict__ tg) {
    __shared__ __align__(16) unsigned short Bs[128][328];
    const int tid = threadIdx.x;
    const int g0 = blockIdx.y * 128;
    // stage B (128 cols x 320 k, zero-padded past 300), f32 -> bf16
    {
        const int col = tid >> 2;
        const int kq = tid & 3;
        const float* wrow = w_ih + (size_t)(g0 + col) * E_;
#pragma unroll 4
        for (int kk = 0; kk < 80; ++kk) {
            int k = kq * 80 + kk;
            Bs[col][k] = (unsigned short)((k < E_) ? f2bf(wrow[k]) : (short)0);
        }
    }
    __syncthreads();

    const int wave = tid >> 6;
    const int lane = tid & 63;
    const int v0 = blockIdx.x * 128 + wave * 16;
    if (v0 >= V_) return;
    const int m = lane & 15;
    const int q = lane >> 4;
    f32x4 acc[8];
#pragma unroll
    for (int gt = 0; gt < 8; ++gt) acc[gt] = (f32x4){0.f, 0.f, 0.f, 0.f};

    const float* arow = table + (size_t)(v0 + m) * E_;

    for (int kt = 0; kt < 9; ++kt) {
        const int e0 = kt * 32 + q * 8;
        const float4 a0 = *(const float4*)(arow + e0);
        const float4 a1 = *(const float4*)(arow + e0 + 4);
        short8 af;
        af[0] = f2bf(a0.x); af[1] = f2bf(a0.y); af[2] = f2bf(a0.z); af[3] = f2bf(a0.w);
        af[4] = f2bf(a1.x); af[5] = f2bf(a1.y); af[6] = f2bf(a1.z); af[7] = f2bf(a1.w);
#pragma unroll
        for (int gt = 0; gt < 8; ++gt) {
            const short8 bf = *(const short8*)&Bs[gt * 16 + m][e0];
            acc[gt] = __builtin_amdgcn_mfma_f32_16x16x32_bf16(af, bf, acc[gt], 0, 0, 0);
        }
    }
    {   // tail: e in [288,320), guard A to e<300; Bs already zero there
        const int e0 = 288 + q * 8;
        short8 af;
#pragma unroll
        for (int jj = 0; jj < 8; ++jj) af[jj] = (e0 + jj < E_) ? f2bf(arow[e0 + jj]) : (short)0;
#pragma unroll
        for (int gt = 0; gt < 8; ++gt) {
            const short8 bf = *(const short8*)&Bs[gt * 16 + m][e0];
            acc[gt] = __builtin_amdgcn_mfma_f32_16x16x32_bf16(af, bf, acc[gt], 0, 0, 0);
        }
    }
#pragma unroll
    for (int gt = 0; gt < 8; ++gt) {
        const int g = g0 + gt * 16 + m;
        const float bias = b_ih[g] + b_hh[g];
#pragma unroll
        for (int r = 0; r < 4; ++r) {
            const int v = v0 + q * 4 + r;
            tg[(size_t)v * G4 + g] = (unsigned short)f2bf((acc[gt][r] + bias) * 512.0f);
        }
    }
}

// ---------------------------------------------------------------------------
// fp8 register-resident LSTM. 16 blocks x 512 thr; block owns 16 batches.
// Per step: gates(16x1024) = h8(16x256,fp8) @ w64(fp8, resident in VGPRs)
// accumulated onto 512*xgates; one barrier/step; fused emissions (waves 0,1).
// ---------------------------------------------------------------------------
__global__ __launch_bounds__(512, 2) void lstm_fp8(const unsigned short* __restrict__ tg,
                                                   const ulonglong2* __restrict__ wB8,
                                                   const int* __restrict__ words,
                                                   const unsigned long long* __restrict__ linB8,
                                                   const float* __restrict__ lin_b,
                                                   float* __restrict__ em,
                                                   int dir) {
    __shared__ __align__(16) unsigned char hbuf[2][16][264];
    const int tid = threadIdx.x;
    const int wv = tid >> 6;
    const int lane = tid & 63;
    const int n = lane & 15;
    const int q = lane >> 4;
    const int b0 = blockIdx.x * 16;

    for (int i = tid; i < 2 * 16 * 264; i += 512) (&hbuf[0][0][0])[i] = 0;
    __syncthreads();

    float cst[2][4];
#pragma unroll
    for (int jt = 0; jt < 2; ++jt)
#pragma unroll
        for (int r = 0; r < 4; ++r) cst[jt][r] = 0.0f;

    const int l0 = dir ? (L_ - 1) : 0;
    const int dl = dir ? -1 : 1;

    // resident fp8 weight B-frags: wfrag[kt*4+gt].x -> jt=0, .y -> jt=1
    ulonglong2 wfrag[32];
    {
        const ulonglong2* wbase = wB8 + (size_t)dir * 16384 + (size_t)wv * 2048;
#pragma unroll
        for (int i = 0; i < 32; ++i) wfrag[i] = wbase[i * 64 + lane];
    }

    int gcol[4][2];
#pragma unroll
    for (int gt = 0; gt < 4; ++gt)
#pragma unroll
        for (int jt = 0; jt < 2; ++jt) gcol[gt][jt] = gt * 256 + wv * 32 + jt * 16 + n;

    const unsigned long long* lfrag = linB8 + (size_t)(dir * 2 + wv) * 512;
    float lbv = 0.0f;
    const int t_em = wv * 16 + n;
    if (wv < 2 && t_em < T_) lbv = lin_b[t_em];

    // preamble: tg for step 0, words for step 1
    unsigned int tgr[4][2][4];
    int wnxt[4];
    {
        int w0[4];
#pragma unroll
        for (int r = 0; r < 4; ++r) w0[r] = words[l0 * B_ + b0 + q * 4 + r];
#pragma unroll
        for (int gt = 0; gt < 4; ++gt)
#pragma unroll
            for (int jt = 0; jt < 2; ++jt)
#pragma unroll
                for (int r = 0; r < 4; ++r)
                    tgr[gt][jt][r] = tg[(size_t)w0[r] * G4 + gcol[gt][jt]];
#pragma unroll
        for (int r = 0; r < 4; ++r) wnxt[r] = words[(l0 + dl) * B_ + b0 + q * 4 + r];
    }

    int p = 0;
    for (int step = 0; step < L_; ++step) {
        const int l = l0 + dl * step;
        // acc init = 512*xgates (consumes tgr immediately)
        f32x4 acc[4][2];
#pragma unroll
        for (int gt = 0; gt < 4; ++gt)
#pragma unroll
            for (int jt = 0; jt < 2; ++jt)
#pragma unroll
                for (int r = 0; r < 4; ++r) acc[gt][jt][r] = bf2f(tgr[gt][jt][r]);

        // prefetch next step's tg (full-step latency cover) and step+2 words
        if (step + 1 < L_) {
#pragma unroll
            for (int gt = 0; gt < 4; ++gt)
#pragma unroll
                for (int jt = 0; jt < 2; ++jt)
#pragma unroll
                    for (int r = 0; r < 4; ++r)
                        tgr[gt][jt][r] = tg[(size_t)wnxt[r] * G4 + gcol[gt][jt]];
        }
        int wtmp[4] = {0, 0, 0, 0};
        if (step + 2 < L_) {
            const int lnn = l + 2 * dl;
#pragma unroll
            for (int r = 0; r < 4; ++r) wtmp[r] = words[lnn * B_ + b0 + q * 4 + r];
        }

#pragma unroll
        for (int kt = 0; kt < 8; ++kt) {
            const unsigned long long af = *(const unsigned long long*)&hbuf[p][n][kt * 32 + q * 8];
#pragma unroll
            for (int gt = 0; gt < 4; ++gt) {
                acc[gt][0] = __builtin_amdgcn_mfma_f32_16x16x32_fp8_fp8(
                    (long long)af, (long long)wfrag[kt * 4 + gt].x, acc[gt][0], 0, 0, 0);
                acc[gt][1] = __builtin_amdgcn_mfma_f32_16x16x32_fp8_fp8(
                    (long long)af, (long long)wfrag[kt * 4 + gt].y, acc[gt][1], 0, 0, 0);
            }
        }

        // gates + state update + h write (fp8, x8)
#pragma unroll
        for (int jt = 0; jt < 2; ++jt)
#pragma unroll
            for (int r = 0; r < 4; ++r) {
                const float ig = sigm(acc[0][jt][r] * (1.0f / 512.0f));
                const float fg = sigm(acc[1][jt][r] * (1.0f / 512.0f));
                const float gg = tanh_(acc[2][jt][r] * (1.0f / 512.0f));
                const float og = sigm(acc[3][jt][r] * (1.0f / 512.0f));
                const float cn = fg * cst[jt][r] + ig * gg;
                cst[jt][r] = cn;
                const float h = og * tanh_(cn);
                hbuf[p ^ 1][q * 4 + r][wv * 32 + jt * 16 + n] = (unsigned char)f2fp8(h * 8.0f);
            }
        __syncthreads();

        // fused emissions (waves 0,1): em = h8 . lin32 / 256 (+ lin_b on fwd)
        if (wv < 2) {
            f32x4 eacc = (f32x4){0.f, 0.f, 0.f, 0.f};
#pragma unroll
            for (int kt = 0; kt < 8; ++kt) {
                const unsigned long long af = *(const unsigned long long*)&hbuf[p ^ 1][n][kt * 32 + q * 8];
                eacc = __builtin_amdgcn_mfma_f32_16x16x32_fp8_fp8(
                    (long long)af, (long long)lfrag[kt * 64 + lane], eacc, 0, 0, 0);
            }
            if (t_em < T_) {
#pragma unroll
                for (int r = 0; r < 4; ++r) {
                    float* ep = em + ((size_t)l * B_ + b0 + q * 4 + r) * T_ + t_em;
                    const float v = eacc[r] * (1.0f / 256.0f);
                    if (dir == 0) *ep = v + lbv;
                    else *ep += v;
                }
            }
        }

#pragma unroll
        for (int r = 0; r < 4; ++r) wnxt[r] = wtmp[r];
        p ^= 1;
    }
}

// ---------------------------------------------------------------------------
// CRF: one 64-thread wave per sequence. (unchanged — verified)
// ---------------------------------------------------------------------------
__global__ __launch_bounds__(64) void crf_kernel(const float* __restrict__ em,
                                                 const int* __restrict__ tags,
                                                 const int* __restrict__ mask,
                                                 const float* __restrict__ start_trans,
                                                 const float* __restrict__ end_trans,
                                                 const float* __restrict__ trans,
                                                 float* __restrict__ llh) {
    const int b = blockIdx.x;
    const int t = threadIdx.x;
    __shared__ float tr[T_ * T_];
    for (int i = t; i < T_ * T_; i += 64) tr[i] = trans[i];
    __syncthreads();

    float part = 0.0f;
    int msum = 0;
    for (int l = t; l < L_; l += 64) {
        const int idx = l * B_ + b;
        const int m = mask[idx];
        msum += m;
        const int tl = tags[idx];
        const float emt = em[(size_t)idx * T_ + tl];
        if (l == 0) {
            part += start_trans[tl] + emt;
        } else {
            const int tp = tags[(l - 1) * B_ + b];
            part += m ? (tr[tp * T_ + tl] + emt) : 0.0f;
        }
    }
    for (int o = 32; o; o >>= 1) {
        part += __shfl_down(part, o);
        msum += __shfl_down(msum, o);
    }

    const int tc = (t < T_) ? t : (T_ - 1);
    float alpha = start_trans[tc] + em[(size_t)b * T_ + tc];
    for (int l = 1; l < L_; ++l) {
        if (mask[l * B_ + b] == 0) break;
        const float emt = em[((size_t)l * B_ + b) * T_ + tc];
        float mx = -1e30f;
#pragma unroll
        for (int s = 0; s < T_; ++s) {
            const float as = __shfl(alpha, s);
            mx = fmaxf(mx, as + tr[s * T_ + tc]);
        }
        float sm = 0.0f;
#pragma unroll
        for (int s = 0; s < T_; ++s) {
            const float as = __shfl(alpha, s);
            sm += __expf(as + tr[s * T_ + tc] - mx);
        }
        alpha = mx + __logf(sm) + emt;
    }
    float val = (t < T_) ? (alpha + end_trans[t]) : -1e30f;
    float mx = val;
    for (int o = 32; o; o >>= 1) mx = fmaxf(mx, __shfl_down(mx, o));
    const float mx_all = __shfl(mx, 0);
    float sm = __expf(val - mx_all);
    for (int o = 32; o; o >>= 1) sm += __shfl_down(sm, o);

    if (t == 0) {
        const float score = part + end_trans[tags[(msum - 1) * B_ + b]];
        const float logZ = mx_all + __logf(sm);
        llh[b] = score - logZ;
    }
}

__global__ __launch_bounds__(256) void final_reduce(const float* __restrict__ llh,
                                                    float* __restrict__ out) {
    const int t = threadIdx.x;
    float v = llh[t];
    for (int o = 32; o; o >>= 1) v += __shfl_down(v, o);
    __shared__ float wsum[4];
    if ((t & 63) == 0) wsum[t >> 6] = v;
    __syncthreads();
    if (t == 0) out[0] = -(wsum[0] + wsum[1] + wsum[2] + wsum[3]);
}

// ---------------------------------------------------------------------------
extern "C" void kernel_launch(void* const* d_in, const int* in_sizes, int n_in,
                              void* d_out, int out_size, void* d_ws, size_t ws_size,
                              hipStream_t stream) {
    const int* words = (const int*)d_in[0];
    const int* tags = (const int*)d_in[1];
    const int* mask = (const int*)d_in[2];
    const float* table = (const float*)d_in[3];
    const float* w_ih_f = (const float*)d_in[4];
    const float* w_hh_f = (const float*)d_in[5];
    const float* b_ih_f = (const float*)d_in[6];
    const float* b_hh_f = (const float*)d_in[7];
    const float* w_ih_b = (const float*)d_in[8];
    const float* w_hh_b = (const float*)d_in[9];
    const float* b_ih_b = (const float*)d_in[10];
    const float* b_hh_b = (const float*)d_in[11];
    const float* lin_w = (const float*)d_in[12];
    const float* lin_b = (const float*)d_in[13];
    const float* start_trans = (const float*)d_in[14];
    const float* end_trans = (const float*)d_in[15];
    const float* trans = (const float*)d_in[16];

    char* ws = (char*)d_ws;
    unsigned short* tg = (unsigned short*)ws;                  // 102,400,000 B
    unsigned char* wB8 = (unsigned char*)(ws + 102400000);     //     524,288 B
    unsigned char* linB8 = (unsigned char*)(ws + 102924288);   //      16,384 B
    float* em = (float*)(ws + 102940672);                      //   4,456,448 B
    float* llh = (float*)(ws + 107397120);                     //       1,024 B
    // total ws use: 107,398,144 B (under round-1's verified 107.9 MB)

    prep_all<<<2112, 256, 0, stream>>>(w_hh_f, w_hh_b, lin_w, wB8, linB8);

    // forward direction
    tg_gemm<<<dim3(391, 8), 512, 0, stream>>>(table, w_ih_f, b_ih_f, b_hh_f, tg);
    lstm_fp8<<<16, 512, 0, stream>>>(tg, (const ulonglong2*)wB8, words,
                                     (const unsigned long long*)linB8, lin_b, em, 0);

    // backward direction (reuses tg; stream order serializes)
    tg_gemm<<<dim3(391, 8), 512, 0, stream>>>(table, w_ih_b, b_ih_b, b_hh_b, tg);
    lstm_fp8<<<16, 512, 0, stream>>>(tg, (const ulonglong2*)wB8, words,
                                     (const unsigned long long*)linB8, lin_b, em, 1);

    crf_kernel<<<256, 64, 0, stream>>>(em, tags, mask, start_trans, end_trans, trans, llh);
    final_reduce<<<1, 256, 0, stream>>>(llh, (float*)d_out);
}

// Round 5
// 1166.905 us; speedup vs baseline: 6.7728x; 2.9043x over previous
//
#include <hip/hip_runtime.h>

#define L_ 256
#define B_ 256
#define V_ 50000
#define E_ 300
#define H_ 256
#define T_ 17
#define G4 1024  // 4*H

typedef short short8 __attribute__((ext_vector_type(8)));
typedef float f32x4 __attribute__((ext_vector_type(4)));
typedef float f32x2 __attribute__((ext_vector_type(2)));
typedef unsigned long long ull;

static __device__ __forceinline__ short f2bf(float x) {
    unsigned int u = __float_as_uint(x);
    u = (u + 0x7fffu + ((u >> 16) & 1u)) >> 16;   // RNE to bf16
    return (short)u;
}
static __device__ __forceinline__ float bf2f(unsigned int u) {
    return __uint_as_float(u << 16);
}

#if __has_builtin(__builtin_amdgcn_exp2f)
#define EXP2(x) __builtin_amdgcn_exp2f(x)
#else
#define EXP2(x) __expf(0.6931471805599453f * (x))
#endif
#if __has_builtin(__builtin_amdgcn_rcpf)
#define RCP(x) __builtin_amdgcn_rcpf(x)
#else
#define RCP(x) (1.0f / (x))
#endif

static __device__ __forceinline__ float sigm(float x) {
    return RCP(1.0f + EXP2(-1.4426950408889634f * x));
}
static __device__ __forceinline__ float tanh_(float x) {
    return fmaf(-2.0f, RCP(EXP2(2.8853900817779268f * x) + 1.0f), 1.0f);
}

// f32 -> OCP e4m3fn, RNE, finite input; clamps to +-448. (fallback path)
static __device__ __forceinline__ unsigned int f2fp8(float x) {
    float ax = fminf(fabsf(x), 448.0f);
    int e = (int)(__float_as_uint(ax) >> 23) - 127;
    int ec = e < -6 ? -6 : e;
    float sc = __uint_as_float((unsigned int)(130 - ec) << 23);
    float t = __builtin_fmaf(ax, sc, 12582912.0f);
    int n = (int)(__float_as_uint(t) & 0x3fffff);
    int code = ((ec + 7) << 3) + n - 8;
    return (unsigned int)code | ((__float_as_uint(x) >> 24) & 0x80);
}
// pack two f32 -> two e4m3 bytes (low16 of result)
static __device__ __forceinline__ unsigned int pk_fp8(float a, float b) {
#if __has_builtin(__builtin_amdgcn_cvt_pk_fp8_f32)
    return (unsigned int)__builtin_amdgcn_cvt_pk_fp8_f32(a, b, 0, false) & 0xffffu;
#else
    return f2fp8(a) | (f2fp8(b) << 8);
#endif
}
static __device__ __forceinline__ float dec8(unsigned int b) {
    unsigned int f = ((b & 0x7fu) << 20) + 0x3C000000u;
    f |= (b & 0x80u) << 24;
    return __uint_as_float(f);
}
// decode packed e4m3 pair; HI as template param (builtin needs an ICE operand)
template <bool HI>
static __device__ __forceinline__ f32x2 pk_f32(unsigned int u) {
#if __has_builtin(__builtin_amdgcn_cvt_pk_f32_fp8)
    return __builtin_amdgcn_cvt_pk_f32_fp8((int)u, HI);
#else
    f32x2 r;
    r.x = dec8((u >> (HI ? 16 : 0)) & 0xff);
    r.y = dec8((u >> (HI ? 24 : 8)) & 0xff);
    return r;
#endif
}

// ---------------------------------------------------------------------------
// prep_all: w_hh (both dirs, x8) -> fp8 B-frags for the 16-wave LSTM;
// lin_w (x32) -> fp8 B-frags for fused emissions.
// wB8 byte = dir*262144 + wv*16384 + kt*2048 + gt*512 + lane*8 + j
//   g = gt*256 + wv*16 + (lane&15); k = kt*32 + (lane>>4)*8 + j
// linB8 byte = (dir*2+wv)*4096 + kt*512 + lane*8 + j  (t = wv*16+(lane&15))
// ---------------------------------------------------------------------------
__global__ __launch_bounds__(256) void prep_all(const float* __restrict__ whf,
                                                const float* __restrict__ whb,
                                                const float* __restrict__ lin_w,
                                                unsigned char* __restrict__ wB8,
                                                unsigned char* __restrict__ linB8) {
    int gid = blockIdx.x * 256 + threadIdx.x;
    if (gid < 524288) {
        int j = gid & 7;
        int lane = (gid >> 3) & 63;
        int gt = (gid >> 9) & 3;
        int kt = (gid >> 11) & 7;
        int wv = (gid >> 14) & 15;
        int dir = gid >> 18;
        int g = gt * 256 + wv * 16 + (lane & 15);
        int k = kt * 32 + (lane >> 4) * 8 + j;
        const float* w = dir ? whb : whf;
        wB8[gid] = (unsigned char)f2fp8(w[g * H_ + k] * 8.0f);
    } else {
        int i2 = gid - 524288;  // < 16384
        int dir = (i2 >> 13) & 1;
        int wv = (i2 >> 12) & 1;
        int kt = (i2 >> 9) & 7;
        int lane = (i2 >> 3) & 63;
        int j = i2 & 7;
        int t = wv * 16 + (lane & 15);
        int k = kt * 32 + (lane >> 4) * 8 + j;
        float v = (t < T_) ? lin_w[t * (2 * H_) + dir * H_ + k] * 32.0f : 0.0f;
        linB8[i2] = (unsigned char)f2fp8(v);
    }
}

// ---------------------------------------------------------------------------
// prep_bih: w_ih (one dir) -> bf16 B-frags (zero-padded K to 320).
// flat ushort idx = gtile*5120 + kt*512 + lane*8 + j  (gtile<64, kt<10)
//   g = gtile*16 + (lane&15); k = kt*32 + (lane>>4)*8 + j
// ---------------------------------------------------------------------------
__global__ __launch_bounds__(256) void prep_bih(const float* __restrict__ w_ih,
                                                unsigned short* __restrict__ dst) {
    int i = blockIdx.x * 256 + threadIdx.x;  // exactly 327680
    int gtile = i / 5120;
    int r = i - gtile * 5120;
    int kt = r >> 9;
    int lane = (r >> 3) & 63;
    int j = r & 7;
    int g = gtile * 16 + (lane & 15);
    int k = kt * 32 + (lane >> 4) * 8 + j;
    dst[i] = (unsigned short)((k < E_) ? f2bf(w_ih[g * E_ + k]) : (short)0);
}

// ---------------------------------------------------------------------------
// tg_gemm: tg8[v][perm(g)] = e4m3( 64*(sum_e table[v][e]*w_ih[g][e] + bias_g) )
// perm(g): byte = ((g>>4)&15)*64 + (g&15)*4 + (g>>8)  -- so the LSTM's dword
// gather gets {i,f,g,o} for one hidden j in one load.
// Block 512 thr = 8 waves x 16 v-rows; no LDS (B-frags pre-packed, L2-hot).
// ---------------------------------------------------------------------------
__global__ __launch_bounds__(512) void tg_gemm(const float* __restrict__ table,
                                               const unsigned short* __restrict__ wBih,
                                               const float* __restrict__ b_ih,
                                               const float* __restrict__ b_hh,
                                               unsigned char* __restrict__ tg8) {
    const int wave = threadIdx.x >> 6;
    const int lane = threadIdx.x & 63;
    const int v0 = blockIdx.x * 128 + wave * 16;
    if (v0 >= V_) return;
    const int g0 = blockIdx.y * 128;
    const int m = lane & 15;
    const int q = lane >> 4;
    f32x4 acc[8];
#pragma unroll
    for (int gt = 0; gt < 8; ++gt) acc[gt] = (f32x4){0.f, 0.f, 0.f, 0.f};

    const float* arow = table + (size_t)(v0 + m) * E_;

#pragma unroll 1
    for (int kt = 0; kt < 9; ++kt) {
        const int e0 = kt * 32 + q * 8;
        const float4 a0 = *(const float4*)(arow + e0);
        const float4 a1 = *(const float4*)(arow + e0 + 4);
        short8 af;
        af[0] = f2bf(a0.x); af[1] = f2bf(a0.y); af[2] = f2bf(a0.z); af[3] = f2bf(a0.w);
        af[4] = f2bf(a1.x); af[5] = f2bf(a1.y); af[6] = f2bf(a1.z); af[7] = f2bf(a1.w);
#pragma unroll
        for (int gt = 0; gt < 8; ++gt) {
            const short8 bf = *(const short8*)(wBih + (size_t)(blockIdx.y * 8 + gt) * 5120 + kt * 512 + lane * 8);
            acc[gt] = __builtin_amdgcn_mfma_f32_16x16x32_bf16(af, bf, acc[gt], 0, 0, 0);
        }
    }
    {   // K tail [288,320): guard A to e<300; B frags already zero there
        const int e0 = 288 + q * 8;
        short8 af;
#pragma unroll
        for (int jj = 0; jj < 8; ++jj) af[jj] = (e0 + jj < E_) ? f2bf(arow[e0 + jj]) : (short)0;
#pragma unroll
        for (int gt = 0; gt < 8; ++gt) {
            const short8 bf = *(const short8*)(wBih + (size_t)(blockIdx.y * 8 + gt) * 5120 + 9 * 512 + lane * 8);
            acc[gt] = __builtin_amdgcn_mfma_f32_16x16x32_bf16(af, bf, acc[gt], 0, 0, 0);
        }
    }
#pragma unroll
    for (int gt = 0; gt < 8; ++gt) {
        const int g = g0 + gt * 16 + m;
        const float bias = b_ih[g] + b_hh[g];
        const int off = ((g >> 4) & 15) * 64 + (g & 15) * 4 + (g >> 8);
        float vals[4];
#pragma unroll
        for (int r = 0; r < 4; ++r) vals[r] = (acc[gt][r] + bias) * 64.0f;
        unsigned int p01 = pk_fp8(vals[0], vals[1]);
        unsigned int p23 = pk_fp8(vals[2], vals[3]);
        unsigned char bytes[4] = {(unsigned char)(p01 & 0xff), (unsigned char)(p01 >> 8),
                                  (unsigned char)(p23 & 0xff), (unsigned char)(p23 >> 8)};
#pragma unroll
        for (int r = 0; r < 4; ++r)
            tg8[(size_t)(v0 + q * 4 + r) * 1024 + off] = bytes[r];
    }
}

// ---------------------------------------------------------------------------
// Merged fp8 LSTM, both directions in one launch. 32 blocks x 1024 thr
// (16 waves): blocks 0-15 fwd, 16-31 bwd; block owns 16 batches.
// Wave wv owns gate cols {gt*256 + wv*16 + n} -> i,f,g,o for hidden
// j = wv*16+n in-lane. Weights register-resident (64 VGPR/wave).
// ---------------------------------------------------------------------------
__global__ __launch_bounds__(1024, 4) void lstm_fp8(const unsigned char* __restrict__ tg8,
                                                    const ull* __restrict__ wB8,
                                                    const int* __restrict__ words,
                                                    const ull* __restrict__ linB8,
                                                    unsigned short* __restrict__ emf,
                                                    unsigned short* __restrict__ emb) {
    __shared__ __align__(16) unsigned char hbuf[2][16][264];
    const int tid = threadIdx.x;
    const int wv = tid >> 6;
    const int lane = tid & 63;
    const int n = lane & 15;
    const int q = lane >> 4;
    const int dir = blockIdx.x >> 4;
    const int b0 = (blockIdx.x & 15) * 16;

    for (int i = tid; i < 2 * 16 * 264; i += 1024) (&hbuf[0][0][0])[i] = 0;
    __syncthreads();

    float cst[4] = {0.f, 0.f, 0.f, 0.f};

    const int l0 = dir ? (L_ - 1) : 0;
    const int dl = dir ? -1 : 1;

    // resident weights: wfrag[kt*4+gt]
    ull wfrag[32];
    {
        const ull* wbase = wB8 + (size_t)dir * 32768 + (size_t)wv * 2048 + lane;
#pragma unroll
        for (int i = 0; i < 32; ++i) wfrag[i] = wbase[i * 64];
    }

    const unsigned char* tgd = tg8 + (size_t)dir * 51200000;
    const int laneoff = wv * 64 + n * 4;
    unsigned short* emx = dir ? emb : emf;
    const ull* lfrag = linB8 + (size_t)(dir * 2 + wv) * 512 + lane;
    const int t_em = wv * 16 + n;

    // preamble: tg dwords for step 0, words for step 1
    unsigned int tgr[4];
    int wnxt[4];
    {
        int w0[4];
#pragma unroll
        for (int r = 0; r < 4; ++r) w0[r] = words[l0 * B_ + b0 + q * 4 + r];
#pragma unroll
        for (int r = 0; r < 4; ++r)
            tgr[r] = *(const unsigned int*)(tgd + (size_t)w0[r] * 1024 + laneoff);
#pragma unroll
        for (int r = 0; r < 4; ++r) wnxt[r] = words[(l0 + dl) * B_ + b0 + q * 4 + r];
    }

    int p = 0;
    for (int step = 0; step < L_; ++step) {
        const int l = l0 + dl * step;
        // acc init = 64*xgates (decode packed fp8: bytes = i,f,g,o)
        f32x4 acc[4];
#pragma unroll
        for (int r = 0; r < 4; ++r) {
            f32x2 p0 = pk_f32<false>(tgr[r]);
            f32x2 p1 = pk_f32<true>(tgr[r]);
            acc[0][r] = p0.x; acc[1][r] = p0.y; acc[2][r] = p1.x; acc[3][r] = p1.y;
        }

        // prefetch next step's tg dwords + step+2 words
        if (step + 1 < L_) {
#pragma unroll
            for (int r = 0; r < 4; ++r)
                tgr[r] = *(const unsigned int*)(tgd + (size_t)wnxt[r] * 1024 + laneoff);
        }
        int wtmp[4] = {0, 0, 0, 0};
        if (step + 2 < L_) {
            const int lnn = l + 2 * dl;
#pragma unroll
            for (int r = 0; r < 4; ++r) wtmp[r] = words[lnn * B_ + b0 + q * 4 + r];
        }

#pragma unroll
        for (int kt = 0; kt < 8; ++kt) {
            const ull af = *(const ull*)&hbuf[p][n][kt * 32 + q * 8];
#pragma unroll
            for (int gt = 0; gt < 4; ++gt)
                acc[gt] = __builtin_amdgcn_mfma_f32_16x16x32_fp8_fp8(
                    (long long)af, (long long)wfrag[kt * 4 + gt], acc[gt], 0, 0, 0);
        }

        // gates (descale 1/64) + state + h write (fp8 x8)
        float hv[4];
#pragma unroll
        for (int r = 0; r < 4; ++r) {
            const float s = 1.0f / 64.0f;
            const float ig = sigm(acc[0][r] * s);
            const float fg = sigm(acc[1][r] * s);
            const float gg = tanh_(acc[2][r] * s);
            const float og = sigm(acc[3][r] * s);
            const float cn = fmaf(fg, cst[r], ig * gg);
            cst[r] = cn;
            hv[r] = og * tanh_(cn);
        }
        {
            unsigned int p01 = pk_fp8(hv[0] * 8.0f, hv[1] * 8.0f);
            unsigned int p23 = pk_fp8(hv[2] * 8.0f, hv[3] * 8.0f);
            hbuf[p ^ 1][q * 4 + 0][wv * 16 + n] = (unsigned char)(p01 & 0xff);
            hbuf[p ^ 1][q * 4 + 1][wv * 16 + n] = (unsigned char)(p01 >> 8);
            hbuf[p ^ 1][q * 4 + 2][wv * 16 + n] = (unsigned char)(p23 & 0xff);
            hbuf[p ^ 1][q * 4 + 3][wv * 16 + n] = (unsigned char)(p23 >> 8);
        }
        __syncthreads();

        // fused emissions (waves 0,1): em = h8 . lin32 / 256  (no lin_b; CRF adds)
        if (wv < 2) {
            f32x4 eacc = (f32x4){0.f, 0.f, 0.f, 0.f};
#pragma unroll
            for (int kt = 0; kt < 8; ++kt) {
                const ull af = *(const ull*)&hbuf[p ^ 1][n][kt * 32 + q * 8];
                eacc = __builtin_amdgcn_mfma_f32_16x16x32_fp8_fp8(
                    (long long)af, (long long)lfrag[kt * 64], eacc, 0, 0, 0);
            }
            if (t_em < T_) {
#pragma unroll
                for (int r = 0; r < 4; ++r)
                    emx[((size_t)l * B_ + b0 + q * 4 + r) * T_ + t_em] =
                        (unsigned short)f2bf(eacc[r] * (1.0f / 256.0f));
            }
        }

#pragma unroll
        for (int r = 0; r < 4; ++r) wnxt[r] = wtmp[r];
        p ^= 1;
    }
}

// ---------------------------------------------------------------------------
// CRF: one wave per sequence; em = emf + emb + lin_b (bf16 halves).
// Length-based logZ loop (no mask loads), trans column in registers,
// next-step em prefetched.
// ---------------------------------------------------------------------------
__global__ __launch_bounds__(64) void crf_kernel(const unsigned short* __restrict__ emf,
                                                 const unsigned short* __restrict__ emb,
                                                 const int* __restrict__ tags,
                                                 const int* __restrict__ mask,
                                                 const float* __restrict__ start_trans,
                                                 const float* __restrict__ end_trans,
                                                 const float* __restrict__ trans,
                                                 const float* __restrict__ lin_b,
                                                 float* __restrict__ llh) {
    const int b = blockIdx.x;
    const int t = threadIdx.x;
    __shared__ float tr[T_ * T_];
    __shared__ float lb[T_];
    for (int i = t; i < T_ * T_; i += 64) tr[i] = trans[i];
    if (t < T_) lb[t] = lin_b[t];
    __syncthreads();

    const int tc = (t < T_) ? t : (T_ - 1);
    const float lbc = lb[tc];
    float trc[T_];
#pragma unroll
    for (int s = 0; s < T_; ++s) trc[s] = tr[s * T_ + tc];

    // numerator + length
    float part = 0.0f;
    int msum = 0;
    for (int l = t; l < L_; l += 64) {
        const int idx = l * B_ + b;
        const int m = mask[idx];
        msum += m;
        const int tl = tags[idx];
        const float emt = bf2f(emf[(size_t)idx * T_ + tl]) + bf2f(emb[(size_t)idx * T_ + tl]) + lb[tl];
        if (l == 0) {
            part += start_trans[tl] + emt;
        } else {
            const int tp = tags[(l - 1) * B_ + b];
            part += m ? (tr[tp * T_ + tl] + emt) : 0.0f;
        }
    }
    for (int o = 32; o; o >>= 1) {
        part += __shfl_down(part, o);
        msum += __shfl_down(msum, o);
    }
    const int len = __shfl(msum, 0);

    // logZ forward scan
    float alpha = start_trans[tc] + bf2f(emf[(size_t)b * T_ + tc]) + bf2f(emb[(size_t)b * T_ + tc]) + lbc;
    float env = 0.0f;
    if (len > 1) {
        const size_t i1 = ((size_t)B_ + b) * T_ + tc;
        env = bf2f(emf[i1]) + bf2f(emb[i1]) + lbc;
    }
    for (int l = 1; l < len; ++l) {
        const float cur = env;
        if (l + 1 < len) {
            const size_t ix = ((size_t)(l + 1) * B_ + b) * T_ + tc;
            env = bf2f(emf[ix]) + bf2f(emb[ix]) + lbc;
        }
        float mx = -1e30f;
#pragma unroll
        for (int s = 0; s < T_; ++s) {
            const float as = __shfl(alpha, s);
            mx = fmaxf(mx, as + trc[s]);
        }
        float sm = 0.0f;
#pragma unroll
        for (int s = 0; s < T_; ++s) {
            const float as = __shfl(alpha, s);
            sm += __expf(as + trc[s] - mx);
        }
        alpha = mx + __logf(sm) + cur;
    }
    float val = (t < T_) ? (alpha + end_trans[t]) : -1e30f;
    float mx = val;
    for (int o = 32; o; o >>= 1) mx = fmaxf(mx, __shfl_down(mx, o));
    const float mx_all = __shfl(mx, 0);
    float sm = __expf(val - mx_all);
    for (int o = 32; o; o >>= 1) sm += __shfl_down(sm, o);

    if (t == 0) {
        const float score = part + end_trans[tags[(len - 1) * B_ + b]];
        const float logZ = mx_all + __logf(sm);
        llh[b] = score - logZ;
    }
}

__global__ __launch_bounds__(256) void final_reduce(const float* __restrict__ llh,
                                                    float* __restrict__ out) {
    const int t = threadIdx.x;
    float v = llh[t];
    for (int o = 32; o; o >>= 1) v += __shfl_down(v, o);
    __shared__ float wsum[4];
    if ((t & 63) == 0) wsum[t >> 6] = v;
    __syncthreads();
    if (t == 0) out[0] = -(wsum[0] + wsum[1] + wsum[2] + wsum[3]);
}

// ---------------------------------------------------------------------------
extern "C" void kernel_launch(void* const* d_in, const int* in_sizes, int n_in,
                              void* d_out, int out_size, void* d_ws, size_t ws_size,
                              hipStream_t stream) {
    const int* words = (const int*)d_in[0];
    const int* tags = (const int*)d_in[1];
    const int* mask = (const int*)d_in[2];
    const float* table = (const float*)d_in[3];
    const float* w_ih_f = (const float*)d_in[4];
    const float* w_hh_f = (const float*)d_in[5];
    const float* b_ih_f = (const float*)d_in[6];
    const float* b_hh_f = (const float*)d_in[7];
    const float* w_ih_b = (const float*)d_in[8];
    const float* w_hh_b = (const float*)d_in[9];
    const float* b_ih_b = (const float*)d_in[10];
    const float* b_hh_b = (const float*)d_in[11];
    const float* lin_w = (const float*)d_in[12];
    const float* lin_b = (const float*)d_in[13];
    const float* start_trans = (const float*)d_in[14];
    const float* end_trans = (const float*)d_in[15];
    const float* trans = (const float*)d_in[16];

    char* ws = (char*)d_ws;
    unsigned char* tg8 = (unsigned char*)ws;                    // 102,400,000 (2 dirs)
    unsigned char* wB8 = (unsigned char*)(ws + 102400000);      //     524,288
    unsigned char* linB8 = (unsigned char*)(ws + 102924288);    //      16,384
    unsigned short* emf = (unsigned short*)(ws + 102940672);    //   2,228,224
    unsigned short* emb = (unsigned short*)(ws + 105168896);    //   2,228,224
    float* llh = (float*)(ws + 107397120);                      //       1,024
    // total: 107,398,144 B (== round-3 verified footprint)
    // wBih (655,360 B) aliases the emf region during the GEMM phase only.
    unsigned short* wBih = emf;

    prep_all<<<2112, 256, 0, stream>>>(w_hh_f, w_hh_b, lin_w, wB8, linB8);

    prep_bih<<<1280, 256, 0, stream>>>(w_ih_f, wBih);
    tg_gemm<<<dim3(391, 8), 512, 0, stream>>>(table, wBih, b_ih_f, b_hh_f, tg8);

    prep_bih<<<1280, 256, 0, stream>>>(w_ih_b, wBih);
    tg_gemm<<<dim3(391, 8), 512, 0, stream>>>(table, wBih, b_ih_b, b_hh_b, tg8 + 51200000);

    lstm_fp8<<<32, 1024, 0, stream>>>(tg8, (const ull*)wB8, words, (const ull*)linB8, emf, emb);

    crf_kernel<<<256, 64, 0, stream>>>(emf, emb, tags, mask, start_trans, end_trans, trans, lin_b, llh);
    final_reduce<<<1, 256, 0, stream>>>(llh, (float*)d_out);
}

// Round 6
// 1050.395 us; speedup vs baseline: 7.5240x; 1.1109x over previous
//
#include <hip/hip_runtime.h>

#define L_ 256
#define B_ 256
#define V_ 50000
#define E_ 300
#define H_ 256
#define T_ 17
#define G4 1024  // 4*H

typedef short short8 __attribute__((ext_vector_type(8)));
typedef float f32x4 __attribute__((ext_vector_type(4)));
typedef float f32x2 __attribute__((ext_vector_type(2)));
typedef unsigned long long ull;

static __device__ __forceinline__ short f2bf(float x) {
    unsigned int u = __float_as_uint(x);
    u = (u + 0x7fffu + ((u >> 16) & 1u)) >> 16;   // RNE to bf16
    return (short)u;
}
static __device__ __forceinline__ float bf2f(unsigned int u) {
    return __uint_as_float(u << 16);
}

#if __has_builtin(__builtin_amdgcn_exp2f)
#define EXP2(x) __builtin_amdgcn_exp2f(x)
#else
#define EXP2(x) __expf(0.6931471805599453f * (x))
#endif
#if __has_builtin(__builtin_amdgcn_rcpf)
#define RCP(x) __builtin_amdgcn_rcpf(x)
#else
#define RCP(x) (1.0f / (x))
#endif

static __device__ __forceinline__ float sigm(float x) {
    return RCP(1.0f + EXP2(-1.4426950408889634f * x));
}
static __device__ __forceinline__ float tanh_(float x) {
    return fmaf(-2.0f, RCP(EXP2(2.8853900817779268f * x) + 1.0f), 1.0f);
}

// f32 -> OCP e4m3fn, RNE, finite input; clamps to +-448. (fallback path)
static __device__ __forceinline__ unsigned int f2fp8(float x) {
    float ax = fminf(fabsf(x), 448.0f);
    int e = (int)(__float_as_uint(ax) >> 23) - 127;
    int ec = e < -6 ? -6 : e;
    float sc = __uint_as_float((unsigned int)(130 - ec) << 23);
    float t = __builtin_fmaf(ax, sc, 12582912.0f);
    int n = (int)(__float_as_uint(t) & 0x3fffff);
    int code = ((ec + 7) << 3) + n - 8;
    return (unsigned int)code | ((__float_as_uint(x) >> 24) & 0x80);
}
static __device__ __forceinline__ unsigned int pk_fp8(float a, float b) {
#if __has_builtin(__builtin_amdgcn_cvt_pk_fp8_f32)
    return (unsigned int)__builtin_amdgcn_cvt_pk_fp8_f32(a, b, 0, false) & 0xffffu;
#else
    return f2fp8(a) | (f2fp8(b) << 8);
#endif
}
static __device__ __forceinline__ float dec8(unsigned int b) {
    unsigned int f = ((b & 0x7fu) << 20) + 0x3C000000u;
    f |= (b & 0x80u) << 24;
    return __uint_as_float(f);
}
template <bool HI>
static __device__ __forceinline__ f32x2 pk_f32(unsigned int u) {
#if __has_builtin(__builtin_amdgcn_cvt_pk_f32_fp8)
    return __builtin_amdgcn_cvt_pk_f32_fp8((int)u, HI);
#else
    f32x2 r;
    r.x = dec8((u >> (HI ? 16 : 0)) & 0xff);
    r.y = dec8((u >> (HI ? 24 : 8)) & 0xff);
    return r;
#endif
}

// pack two f32 -> bf16 pair (round-half-up via +0x8000, then byte-perm)
static __device__ __forceinline__ unsigned int pk2bf(float x, float y) {
#if __has_builtin(__builtin_amdgcn_perm)
    return __builtin_amdgcn_perm(__float_as_uint(y) + 0x8000u,
                                 __float_as_uint(x) + 0x8000u, 0x07060302u);
#else
    return (unsigned int)(unsigned short)f2bf(x) |
           ((unsigned int)(unsigned short)f2bf(y) << 16);
#endif
}
static __device__ __forceinline__ short8 pack8(float4 a, float4 b) {
    union { unsigned int u[4]; short8 s; } r;
    r.u[0] = pk2bf(a.x, a.y);
    r.u[1] = pk2bf(a.z, a.w);
    r.u[2] = pk2bf(b.x, b.y);
    r.u[3] = pk2bf(b.z, b.w);
    return r.s;
}

// ---------------------------------------------------------------------------
// prep_all: w_hh (both dirs, x8) -> fp8 B-frags; lin_w (x32) -> fp8 B-frags.
// (unchanged from round 5 — verified)
// ---------------------------------------------------------------------------
__global__ __launch_bounds__(256) void prep_all(const float* __restrict__ whf,
                                                const float* __restrict__ whb,
                                                const float* __restrict__ lin_w,
                                                unsigned char* __restrict__ wB8,
                                                unsigned char* __restrict__ linB8) {
    int gid = blockIdx.x * 256 + threadIdx.x;
    if (gid < 524288) {
        int j = gid & 7;
        int lane = (gid >> 3) & 63;
        int gt = (gid >> 9) & 3;
        int kt = (gid >> 11) & 7;
        int wv = (gid >> 14) & 15;
        int dir = gid >> 18;
        int g = gt * 256 + wv * 16 + (lane & 15);
        int k = kt * 32 + (lane >> 4) * 8 + j;
        const float* w = dir ? whb : whf;
        wB8[gid] = (unsigned char)f2fp8(w[g * H_ + k] * 8.0f);
    } else {
        int i2 = gid - 524288;  // < 16384
        int dir = (i2 >> 13) & 1;
        int wv = (i2 >> 12) & 1;
        int kt = (i2 >> 9) & 7;
        int lane = (i2 >> 3) & 63;
        int j = i2 & 7;
        int t = wv * 16 + (lane & 15);
        int k = kt * 32 + (lane >> 4) * 8 + j;
        float v = (t < T_) ? lin_w[t * (2 * H_) + dir * H_ + k] * 32.0f : 0.0f;
        linB8[i2] = (unsigned char)f2fp8(v);
    }
}

// ---------------------------------------------------------------------------
// prep_bih: BOTH dirs' w_ih -> bf16 B-frags (zero-padded K to 320).
// per-dir flat ushort idx = gtile*5120 + kt*512 + lane*8 + j
//   g = gtile*16 + (lane&15); k = kt*32 + (lane>>4)*8 + j
// ---------------------------------------------------------------------------
__global__ __launch_bounds__(256) void prep_bih(const float* __restrict__ w_ih_f,
                                                const float* __restrict__ w_ih_b,
                                                unsigned short* __restrict__ dstf,
                                                unsigned short* __restrict__ dstb) {
    int gid = blockIdx.x * 256 + threadIdx.x;  // 2*327680
    int dir = gid >= 327680;
    int i = gid - dir * 327680;
    int gtile = i / 5120;
    int r = i - gtile * 5120;
    int kt = r >> 9;
    int lane = (r >> 3) & 63;
    int j = r & 7;
    int g = gtile * 16 + (lane & 15);
    int k = kt * 32 + (lane >> 4) * 8 + j;
    const float* src = dir ? w_ih_b : w_ih_f;
    unsigned short* dst = dir ? dstb : dstf;
    dst[i] = (unsigned short)((k < E_) ? f2bf(src[g * E_ + k]) : (short)0);
}

// ---------------------------------------------------------------------------
// tg_gemm v3: both dirs in one launch. Grid (196, 16): y>>3 = dir,
// (y&7)*128 = g0. Block 512 thr = 8 waves; wave = 32 rows x 128 cols.
// B kt-tile (8 frags = 8 KB) staged in LDS double-buffered, 1 barrier/kt;
// wave w stages frag gt=w. A packed to bf16 via v_perm.
// tg8[v][perm(g)] = e4m3(64*(table[v]·w_ih[g] + bias_g))
// ---------------------------------------------------------------------------
__global__ __launch_bounds__(512, 4) void tg_gemm(const float* __restrict__ table,
                                                  const unsigned short* __restrict__ wBihF,
                                                  const unsigned short* __restrict__ wBihB,
                                                  const float* __restrict__ b_ih_f,
                                                  const float* __restrict__ b_hh_f,
                                                  const float* __restrict__ b_ih_b,
                                                  const float* __restrict__ b_hh_b,
                                                  unsigned char* __restrict__ tg8) {
    __shared__ __align__(16) unsigned short Bs[2][8][512];
    const int tid = threadIdx.x;
    const int w = tid >> 6;
    const int lane = tid & 63;
    const int n = lane & 15;
    const int q = lane >> 4;
    const int dir = blockIdx.y >> 3;
    const int g0 = (blockIdx.y & 7) * 128;
    const unsigned short* wB = dir ? wBihB : wBihF;
    const float* bi = dir ? b_ih_b : b_ih_f;
    const float* bh = dir ? b_hh_b : b_hh_f;
    const int v0 = blockIdx.x * 256 + w * 32;

    const int r0 = v0 + n;
    const int r1 = v0 + 16 + n;
    const float* arow0 = table + (size_t)(r0 < V_ ? r0 : V_ - 1) * E_;
    const float* arow1 = table + (size_t)(r1 < V_ ? r1 : V_ - 1) * E_;

    float bias[8];
#pragma unroll
    for (int gt = 0; gt < 8; ++gt) {
        int g = g0 + gt * 16 + n;
        bias[gt] = bi[g] + bh[g];
    }

    const unsigned short* bsrc = wB + (size_t)(g0 / 16 + w) * 5120 + lane * 8;

    f32x4 acc[8][2];
#pragma unroll
    for (int gt = 0; gt < 8; ++gt) {
        acc[gt][0] = (f32x4){0.f, 0.f, 0.f, 0.f};
        acc[gt][1] = (f32x4){0.f, 0.f, 0.f, 0.f};
    }

    short8 breg = *(const short8*)bsrc;  // kt=0 frag slice

#pragma unroll 1
    for (int kt = 0; kt < 10; ++kt) {
        *(short8*)&Bs[kt & 1][w][lane * 8] = breg;
        __syncthreads();
        if (kt < 9) breg = *(const short8*)(bsrc + (kt + 1) * 512);

        short8 af0, af1;
        const int e0 = kt * 32 + q * 8;
        if (kt < 9) {
            const float4 a0 = *(const float4*)(arow0 + e0);
            const float4 a1 = *(const float4*)(arow0 + e0 + 4);
            const float4 b0 = *(const float4*)(arow1 + e0);
            const float4 b1 = *(const float4*)(arow1 + e0 + 4);
            af0 = pack8(a0, a1);
            af1 = pack8(b0, b1);
        } else {
            float va[8], vb[8];
#pragma unroll
            for (int j = 0; j < 8; ++j) {
                const int e = e0 + j;
                va[j] = (e < E_) ? arow0[e] : 0.0f;
                vb[j] = (e < E_) ? arow1[e] : 0.0f;
            }
            af0 = pack8((float4){va[0], va[1], va[2], va[3]},
                        (float4){va[4], va[5], va[6], va[7]});
            af1 = pack8((float4){vb[0], vb[1], vb[2], vb[3]},
                        (float4){vb[4], vb[5], vb[6], vb[7]});
        }

#pragma unroll
        for (int gt = 0; gt < 8; ++gt) {
            const short8 bf = *(const short8*)&Bs[kt & 1][gt][lane * 8];
            acc[gt][0] = __builtin_amdgcn_mfma_f32_16x16x32_bf16(af0, bf, acc[gt][0], 0, 0, 0);
            acc[gt][1] = __builtin_amdgcn_mfma_f32_16x16x32_bf16(af1, bf, acc[gt][1], 0, 0, 0);
        }
    }

    unsigned char* tgd = tg8 + (size_t)dir * 51200000;
#pragma unroll
    for (int gt = 0; gt < 8; ++gt) {
        const int g = g0 + gt * 16 + n;
        const int off = ((g >> 4) & 15) * 64 + n * 4 + (g >> 8);
#pragma unroll
        for (int rt = 0; rt < 2; ++rt) {
            float vals[4];
#pragma unroll
            for (int r = 0; r < 4; ++r) vals[r] = (acc[gt][rt][r] + bias[gt]) * 64.0f;
            const unsigned int p01 = pk_fp8(vals[0], vals[1]);
            const unsigned int p23 = pk_fp8(vals[2], vals[3]);
            const unsigned char bytes[4] = {
                (unsigned char)(p01 & 0xff), (unsigned char)(p01 >> 8),
                (unsigned char)(p23 & 0xff), (unsigned char)(p23 >> 8)};
#pragma unroll
            for (int r = 0; r < 4; ++r) {
                const int v = v0 + rt * 16 + q * 4 + r;
                if (v < V_) tgd[(size_t)v * 1024 + off] = bytes[r];
            }
        }
    }
}

// ---------------------------------------------------------------------------
// Merged fp8 LSTM (round-5 verified structure; minor VALU trims only):
// int4 word loads, 32-bit tg offsets, descale folded into exp2 constants.
// ---------------------------------------------------------------------------
__global__ __launch_bounds__(1024, 4) void lstm_fp8(const unsigned char* __restrict__ tg8,
                                                    const ull* __restrict__ wB8,
                                                    const int* __restrict__ words,
                                                    const ull* __restrict__ linB8,
                                                    unsigned short* __restrict__ emf,
                                                    unsigned short* __restrict__ emb) {
    __shared__ __align__(16) unsigned char hbuf[2][16][264];
    const int tid = threadIdx.x;
    const int wv = tid >> 6;
    const int lane = tid & 63;
    const int n = lane & 15;
    const int q = lane >> 4;
    const int dir = blockIdx.x >> 4;
    const int b0 = (blockIdx.x & 15) * 16;

    for (int i = tid; i < 2 * 16 * 264; i += 1024) (&hbuf[0][0][0])[i] = 0;
    __syncthreads();

    float cst[4] = {0.f, 0.f, 0.f, 0.f};

    const int l0 = dir ? (L_ - 1) : 0;
    const int dl = dir ? -1 : 1;

    ull wfrag[32];
    {
        const ull* wbase = wB8 + (size_t)dir * 32768 + (size_t)wv * 2048 + lane;
#pragma unroll
        for (int i = 0; i < 32; ++i) wfrag[i] = wbase[i * 64];
    }

    const unsigned char* tgd = tg8 + (size_t)dir * 51200000;
    const unsigned int laneoff = wv * 64 + n * 4;
    unsigned short* emx = dir ? emb : emf;
    const ull* lfrag = linB8 + (size_t)(dir * 2 + wv) * 512 + lane;
    const int t_em = wv * 16 + n;

    // folded nonlinearity constants (acc carries x64 gates)
    const float kSig = -1.4426950408889634f / 64.0f;
    const float kTanh = 2.8853900817779268f / 64.0f;

    unsigned int tgr[4];
    int4 wnxt;
    {
        const int4 w04 = *(const int4*)&words[l0 * B_ + b0 + q * 4];
        tgr[0] = *(const unsigned int*)(tgd + (((unsigned)w04.x << 10) + laneoff));
        tgr[1] = *(const unsigned int*)(tgd + (((unsigned)w04.y << 10) + laneoff));
        tgr[2] = *(const unsigned int*)(tgd + (((unsigned)w04.z << 10) + laneoff));
        tgr[3] = *(const unsigned int*)(tgd + (((unsigned)w04.w << 10) + laneoff));
        wnxt = *(const int4*)&words[(l0 + dl) * B_ + b0 + q * 4];
    }

    int p = 0;
    for (int step = 0; step < L_; ++step) {
        const int l = l0 + dl * step;
        f32x4 acc[4];
#pragma unroll
        for (int r = 0; r < 4; ++r) {
            f32x2 p0 = pk_f32<false>(tgr[r]);
            f32x2 p1 = pk_f32<true>(tgr[r]);
            acc[0][r] = p0.x; acc[1][r] = p0.y; acc[2][r] = p1.x; acc[3][r] = p1.y;
        }

        if (step + 1 < L_) {
            tgr[0] = *(const unsigned int*)(tgd + (((unsigned)wnxt.x << 10) + laneoff));
            tgr[1] = *(const unsigned int*)(tgd + (((unsigned)wnxt.y << 10) + laneoff));
            tgr[2] = *(const unsigned int*)(tgd + (((unsigned)wnxt.z << 10) + laneoff));
            tgr[3] = *(const unsigned int*)(tgd + (((unsigned)wnxt.w << 10) + laneoff));
        }
        int4 wtmp = {0, 0, 0, 0};
        if (step + 2 < L_) {
            wtmp = *(const int4*)&words[(l + 2 * dl) * B_ + b0 + q * 4];
        }

#pragma unroll
        for (int kt = 0; kt < 8; ++kt) {
            const ull af = *(const ull*)&hbuf[p][n][kt * 32 + q * 8];
#pragma unroll
            for (int gt = 0; gt < 4; ++gt)
                acc[gt] = __builtin_amdgcn_mfma_f32_16x16x32_fp8_fp8(
                    (long long)af, (long long)wfrag[kt * 4 + gt], acc[gt], 0, 0, 0);
        }

        float hv[4];
#pragma unroll
        for (int r = 0; r < 4; ++r) {
            const float ig = RCP(1.0f + EXP2(acc[0][r] * kSig));
            const float fg = RCP(1.0f + EXP2(acc[1][r] * kSig));
            const float gg = fmaf(-2.0f, RCP(EXP2(acc[2][r] * kTanh) + 1.0f), 1.0f);
            const float og = RCP(1.0f + EXP2(acc[3][r] * kSig));
            const float cn = fmaf(fg, cst[r], ig * gg);
            cst[r] = cn;
            hv[r] = og * tanh_(cn);
        }
        {
            const unsigned int p01 = pk_fp8(hv[0] * 8.0f, hv[1] * 8.0f);
            const unsigned int p23 = pk_fp8(hv[2] * 8.0f, hv[3] * 8.0f);
            hbuf[p ^ 1][q * 4 + 0][wv * 16 + n] = (unsigned char)(p01 & 0xff);
            hbuf[p ^ 1][q * 4 + 1][wv * 16 + n] = (unsigned char)(p01 >> 8);
            hbuf[p ^ 1][q * 4 + 2][wv * 16 + n] = (unsigned char)(p23 & 0xff);
            hbuf[p ^ 1][q * 4 + 3][wv * 16 + n] = (unsigned char)(p23 >> 8);
        }
        __syncthreads();

        if (wv < 2) {
            f32x4 eacc = (f32x4){0.f, 0.f, 0.f, 0.f};
#pragma unroll
            for (int kt = 0; kt < 8; ++kt) {
                const ull af = *(const ull*)&hbuf[p ^ 1][n][kt * 32 + q * 8];
                eacc = __builtin_amdgcn_mfma_f32_16x16x32_fp8_fp8(
                    (long long)af, (long long)lfrag[kt * 64], eacc, 0, 0, 0);
            }
            if (t_em < T_) {
                const size_t embase = ((size_t)l * B_ + b0) * T_ + t_em + (size_t)q * 4 * T_;
#pragma unroll
                for (int r = 0; r < 4; ++r)
                    emx[embase + r * T_] = (unsigned short)f2bf(eacc[r] * (1.0f / 256.0f));
            }
        }

        wnxt = wtmp;
        p ^= 1;
    }
}

// ---------------------------------------------------------------------------
// CRF: one wave per sequence (round-5 verified).
// ---------------------------------------------------------------------------
__global__ __launch_bounds__(64) void crf_kernel(const unsigned short* __restrict__ emf,
                                                 const unsigned short* __restrict__ emb,
                                                 const int* __restrict__ tags,
                                                 const int* __restrict__ mask,
                                                 const float* __restrict__ start_trans,
                                                 const float* __restrict__ end_trans,
                                                 const float* __restrict__ trans,
                                                 const float* __restrict__ lin_b,
                                                 float* __restrict__ llh) {
    const int b = blockIdx.x;
    const int t = threadIdx.x;
    __shared__ float tr[T_ * T_];
    __shared__ float lb[T_];
    for (int i = t; i < T_ * T_; i += 64) tr[i] = trans[i];
    if (t < T_) lb[t] = lin_b[t];
    __syncthreads();

    const int tc = (t < T_) ? t : (T_ - 1);
    const float lbc = lb[tc];
    float trc[T_];
#pragma unroll
    for (int s = 0; s < T_; ++s) trc[s] = tr[s * T_ + tc];

    float part = 0.0f;
    int msum = 0;
    for (int l = t; l < L_; l += 64) {
        const int idx = l * B_ + b;
        const int m = mask[idx];
        msum += m;
        const int tl = tags[idx];
        const float emt = bf2f(emf[(size_t)idx * T_ + tl]) + bf2f(emb[(size_t)idx * T_ + tl]) + lb[tl];
        if (l == 0) {
            part += start_trans[tl] + emt;
        } else {
            const int tp = tags[(l - 1) * B_ + b];
            part += m ? (tr[tp * T_ + tl] + emt) : 0.0f;
        }
    }
    for (int o = 32; o; o >>= 1) {
        part += __shfl_down(part, o);
        msum += __shfl_down(msum, o);
    }
    const int len = __shfl(msum, 0);

    float alpha = start_trans[tc] + bf2f(emf[(size_t)b * T_ + tc]) + bf2f(emb[(size_t)b * T_ + tc]) + lbc;
    float env = 0.0f;
    if (len > 1) {
        const size_t i1 = ((size_t)B_ + b) * T_ + tc;
        env = bf2f(emf[i1]) + bf2f(emb[i1]) + lbc;
    }
    for (int l = 1; l < len; ++l) {
        const float cur = env;
        if (l + 1 < len) {
            const size_t ix = ((size_t)(l + 1) * B_ + b) * T_ + tc;
            env = bf2f(emf[ix]) + bf2f(emb[ix]) + lbc;
        }
        float mx = -1e30f;
#pragma unroll
        for (int s = 0; s < T_; ++s) {
            const float as = __shfl(alpha, s);
            mx = fmaxf(mx, as + trc[s]);
        }
        float sm = 0.0f;
#pragma unroll
        for (int s = 0; s < T_; ++s) {
            const float as = __shfl(alpha, s);
            sm += __expf(as + trc[s] - mx);
        }
        alpha = mx + __logf(sm) + cur;
    }
    float val = (t < T_) ? (alpha + end_trans[t]) : -1e30f;
    float mx = val;
    for (int o = 32; o; o >>= 1) mx = fmaxf(mx, __shfl_down(mx, o));
    const float mx_all = __shfl(mx, 0);
    float sm = __expf(val - mx_all);
    for (int o = 32; o; o >>= 1) sm += __shfl_down(sm, o);

    if (t == 0) {
        const float score = part + end_trans[tags[(len - 1) * B_ + b]];
        const float logZ = mx_all + __logf(sm);
        llh[b] = score - logZ;
    }
}

__global__ __launch_bounds__(256) void final_reduce(const float* __restrict__ llh,
                                                    float* __restrict__ out) {
    const int t = threadIdx.x;
    float v = llh[t];
    for (int o = 32; o; o >>= 1) v += __shfl_down(v, o);
    __shared__ float wsum[4];
    if ((t & 63) == 0) wsum[t >> 6] = v;
    __syncthreads();
    if (t == 0) out[0] = -(wsum[0] + wsum[1] + wsum[2] + wsum[3]);
}

// ---------------------------------------------------------------------------
extern "C" void kernel_launch(void* const* d_in, const int* in_sizes, int n_in,
                              void* d_out, int out_size, void* d_ws, size_t ws_size,
                              hipStream_t stream) {
    const int* words = (const int*)d_in[0];
    const int* tags = (const int*)d_in[1];
    const int* mask = (const int*)d_in[2];
    const float* table = (const float*)d_in[3];
    const float* w_ih_f = (const float*)d_in[4];
    const float* w_hh_f = (const float*)d_in[5];
    const float* b_ih_f = (const float*)d_in[6];
    const float* b_hh_f = (const float*)d_in[7];
    const float* w_ih_b = (const float*)d_in[8];
    const float* w_hh_b = (const float*)d_in[9];
    const float* b_ih_b = (const float*)d_in[10];
    const float* b_hh_b = (const float*)d_in[11];
    const float* lin_w = (const float*)d_in[12];
    const float* lin_b = (const float*)d_in[13];
    const float* start_trans = (const float*)d_in[14];
    const float* end_trans = (const float*)d_in[15];
    const float* trans = (const float*)d_in[16];

    char* ws = (char*)d_ws;
    unsigned char* tg8 = (unsigned char*)ws;                    // 102,400,000 (2 dirs)
    unsigned char* wB8 = (unsigned char*)(ws + 102400000);      //     524,288
    unsigned char* linB8 = (unsigned char*)(ws + 102924288);    //      16,384
    unsigned short* emf = (unsigned short*)(ws + 102940672);    //   2,228,224
    unsigned short* emb = (unsigned short*)(ws + 105168896);    //   2,228,224
    float* llh = (float*)(ws + 107397120);                      //       1,024
    // total: 107,398,144 B (== round-3/5 verified footprint)
    // wBihF/wBihB (655,360 B each) alias emf/emb during the GEMM phase only
    // (emf/emb are first written by lstm_fp8, after tg_gemm completes).
    unsigned short* wBihF = emf;
    unsigned short* wBihB = emb;

    prep_all<<<2112, 256, 0, stream>>>(w_hh_f, w_hh_b, lin_w, wB8, linB8);
    prep_bih<<<2560, 256, 0, stream>>>(w_ih_f, w_ih_b, wBihF, wBihB);

    tg_gemm<<<dim3(196, 16), 512, 0, stream>>>(table, wBihF, wBihB,
                                               b_ih_f, b_hh_f, b_ih_b, b_hh_b, tg8);

    lstm_fp8<<<32, 1024, 0, stream>>>(tg8, (const ull*)wB8, words, (const ull*)linB8, emf, emb);

    crf_kernel<<<256, 64, 0, stream>>>(emf, emb, tags, mask, start_trans, end_trans, trans, lin_b, llh);
    final_reduce<<<1, 256, 0, stream>>>(llh, (float*)d_out);
}

// Round 7
// 915.005 us; speedup vs baseline: 8.6373x; 1.1480x over previous
//
#include <hip/hip_runtime.h>

#define L_ 256
#define B_ 256
#define V_ 50000
#define E_ 300
#define H_ 256
#define T_ 17
#define G4 1024  // 4*H

typedef short short8 __attribute__((ext_vector_type(8)));
typedef float f32x4 __attribute__((ext_vector_type(4)));
typedef float f32x2 __attribute__((ext_vector_type(2)));
typedef unsigned long long ull;

static __device__ __forceinline__ short f2bf(float x) {
    unsigned int u = __float_as_uint(x);
    u = (u + 0x7fffu + ((u >> 16) & 1u)) >> 16;   // RNE to bf16
    return (short)u;
}
static __device__ __forceinline__ float bf2f(unsigned int u) {
    return __uint_as_float(u << 16);
}

#if __has_builtin(__builtin_amdgcn_exp2f)
#define EXP2(x) __builtin_amdgcn_exp2f(x)
#else
#define EXP2(x) __expf(0.6931471805599453f * (x))
#endif
#if __has_builtin(__builtin_amdgcn_rcpf)
#define RCP(x) __builtin_amdgcn_rcpf(x)
#else
#define RCP(x) (1.0f / (x))
#endif

static __device__ __forceinline__ float sigm(float x) {
    return RCP(1.0f + EXP2(-1.4426950408889634f * x));
}
static __device__ __forceinline__ float tanh_(float x) {
    return fmaf(-2.0f, RCP(EXP2(2.8853900817779268f * x) + 1.0f), 1.0f);
}

// f32 -> OCP e4m3fn, RNE, finite input; clamps to +-448. (fallback path)
static __device__ __forceinline__ unsigned int f2fp8(float x) {
    float ax = fminf(fabsf(x), 448.0f);
    int e = (int)(__float_as_uint(ax) >> 23) - 127;
    int ec = e < -6 ? -6 : e;
    float sc = __uint_as_float((unsigned int)(130 - ec) << 23);
    float t = __builtin_fmaf(ax, sc, 12582912.0f);
    int n = (int)(__float_as_uint(t) & 0x3fffff);
    int code = ((ec + 7) << 3) + n - 8;
    return (unsigned int)code | ((__float_as_uint(x) >> 24) & 0x80);
}
static __device__ __forceinline__ unsigned int pk_fp8(float a, float b) {
#if __has_builtin(__builtin_amdgcn_cvt_pk_fp8_f32)
    return (unsigned int)__builtin_amdgcn_cvt_pk_fp8_f32(a, b, 0, false) & 0xffffu;
#else
    return f2fp8(a) | (f2fp8(b) << 8);
#endif
}
static __device__ __forceinline__ float dec8(unsigned int b) {
    unsigned int f = ((b & 0x7fu) << 20) + 0x3C000000u;
    f |= (b & 0x80u) << 24;
    return __uint_as_float(f);
}
template <bool HI>
static __device__ __forceinline__ f32x2 pk_f32(unsigned int u) {
#if __has_builtin(__builtin_amdgcn_cvt_pk_f32_fp8)
    return __builtin_amdgcn_cvt_pk_f32_fp8((int)u, HI);
#else
    f32x2 r;
    r.x = dec8((u >> (HI ? 16 : 0)) & 0xff);
    r.y = dec8((u >> (HI ? 24 : 8)) & 0xff);
    return r;
#endif
}

// pack two f32 -> bf16 pair (round-half-up via +0x8000, then byte-perm)
static __device__ __forceinline__ unsigned int pk2bf(float x, float y) {
#if __has_builtin(__builtin_amdgcn_perm)
    return __builtin_amdgcn_perm(__float_as_uint(y) + 0x8000u,
                                 __float_as_uint(x) + 0x8000u, 0x07060302u);
#else
    return (unsigned int)(unsigned short)f2bf(x) |
           ((unsigned int)(unsigned short)f2bf(y) << 16);
#endif
}
static __device__ __forceinline__ short8 pack8(float4 a, float4 b) {
    union { unsigned int u[4]; short8 s; } r;
    r.u[0] = pk2bf(a.x, a.y);
    r.u[1] = pk2bf(a.z, a.w);
    r.u[2] = pk2bf(b.x, b.y);
    r.u[3] = pk2bf(b.z, b.w);
    return r.s;
}

// ---------------------------------------------------------------------------
// prep_all: w_hh (both dirs, x8) -> fp8 B-frags; lin_w (x32) -> fp8 B-frags.
// (unchanged — verified)
// ---------------------------------------------------------------------------
__global__ __launch_bounds__(256) void prep_all(const float* __restrict__ whf,
                                                const float* __restrict__ whb,
                                                const float* __restrict__ lin_w,
                                                unsigned char* __restrict__ wB8,
                                                unsigned char* __restrict__ linB8) {
    int gid = blockIdx.x * 256 + threadIdx.x;
    if (gid < 524288) {
        int j = gid & 7;
        int lane = (gid >> 3) & 63;
        int gt = (gid >> 9) & 3;
        int kt = (gid >> 11) & 7;
        int wv = (gid >> 14) & 15;
        int dir = gid >> 18;
        int g = gt * 256 + wv * 16 + (lane & 15);
        int k = kt * 32 + (lane >> 4) * 8 + j;
        const float* w = dir ? whb : whf;
        wB8[gid] = (unsigned char)f2fp8(w[g * H_ + k] * 8.0f);
    } else {
        int i2 = gid - 524288;  // < 16384
        int dir = (i2 >> 13) & 1;
        int wv = (i2 >> 12) & 1;
        int kt = (i2 >> 9) & 7;
        int lane = (i2 >> 3) & 63;
        int j = i2 & 7;
        int t = wv * 16 + (lane & 15);
        int k = kt * 32 + (lane >> 4) * 8 + j;
        float v = (t < T_) ? lin_w[t * (2 * H_) + dir * H_ + k] * 32.0f : 0.0f;
        linB8[i2] = (unsigned char)f2fp8(v);
    }
}

// ---------------------------------------------------------------------------
// prep_bih: BOTH dirs' w_ih -> bf16 B-frags (zero-padded K to 320).
// per-dir flat ushort idx = gtile*5120 + kt*512 + lane*8 + j
//   g = gtile*16 + (lane&15); k = kt*32 + (lane>>4)*8 + j
// ---------------------------------------------------------------------------
__global__ __launch_bounds__(256) void prep_bih(const float* __restrict__ w_ih_f,
                                                const float* __restrict__ w_ih_b,
                                                unsigned short* __restrict__ dstf,
                                                unsigned short* __restrict__ dstb) {
    int gid = blockIdx.x * 256 + threadIdx.x;  // 2*327680
    int dir = gid >= 327680;
    int i = gid - dir * 327680;
    int gtile = i / 5120;
    int r = i - gtile * 5120;
    int kt = r >> 9;
    int lane = (r >> 3) & 63;
    int j = r & 7;
    int g = gtile * 16 + (lane & 15);
    int k = kt * 32 + (lane >> 4) * 8 + j;
    const float* src = dir ? w_ih_b : w_ih_f;
    unsigned short* dst = dir ? dstb : dstf;
    dst[i] = (unsigned short)((k < E_) ? f2bf(src[g * E_ + k]) : (short)0);
}

// ---------------------------------------------------------------------------
// tg_gemm v4: ONE launch, both dirs + all 4 gate types per block.
// Grid (196, 8): jt0 = blockIdx.y*2; block covers jt in {jt0,jt0+1}, gt 0..3,
// dir 0..1 (16 B-frag cols) x 256 rows. 512 thr = 8 waves; wave = 32 rows.
// acc[jj][gt][rt][dir] = 32 f32x4 = 128 VGPR; __launch_bounds__(512,2) so no
// spill. A (f32) and B frags register-prefetched one kt ahead; B staged in
// LDS double-buffered (16 KB/buf), each frag read once per kt (used 2x).
// Epilogue: {i,f,g,o} of hidden j are all in-lane -> single dword store per
// (v, j): tg[v*1024 + (j>>4)*64 + (j&15)*4] = 4 fp8 bytes (lstm gather fmt).
// ---------------------------------------------------------------------------
__global__ __launch_bounds__(512, 2) void tg_gemm(const float* __restrict__ table,
                                                  const unsigned short* __restrict__ wBihF,
                                                  const unsigned short* __restrict__ wBihB,
                                                  const float* __restrict__ b_ih_f,
                                                  const float* __restrict__ b_hh_f,
                                                  const float* __restrict__ b_ih_b,
                                                  const float* __restrict__ b_hh_b,
                                                  unsigned char* __restrict__ tg8) {
    __shared__ __align__(16) unsigned short Bs[2][16][512];
    const int tid = threadIdx.x;
    const int w = tid >> 6;
    const int lane = tid & 63;
    const int n = lane & 15;
    const int q = lane >> 4;
    const int jt0 = blockIdx.y * 2;
    const int v0 = blockIdx.x * 256 + w * 32;

    const int r0 = v0 + n;
    const int r1 = v0 + 16 + n;
    const float* arow0 = table + (size_t)(r0 < V_ ? r0 : V_ - 1) * E_;
    const float* arow1 = table + (size_t)(r1 < V_ ? r1 : V_ - 1) * E_;

    // this wave stages frags f = w and w+8;  f = dir*8 + jj*4 + gt
    const unsigned short* bsrc[2];
#pragma unroll
    for (int s = 0; s < 2; ++s) {
        const int f = w + s * 8;
        const int dir = f >> 3, jj = (f >> 2) & 1, gt = f & 3;
        const int gtile = gt * 16 + jt0 + jj;
        bsrc[s] = (dir ? wBihB : wBihF) + (size_t)gtile * 5120 + lane * 8;
    }

    f32x4 acc[2][4][2][2];  // [jj][gt][rt][dir]
#pragma unroll
    for (int jj = 0; jj < 2; ++jj)
#pragma unroll
        for (int gt = 0; gt < 4; ++gt)
#pragma unroll
            for (int rt = 0; rt < 2; ++rt)
#pragma unroll
                for (int d = 0; d < 2; ++d)
                    acc[jj][gt][rt][d] = (f32x4){0.f, 0.f, 0.f, 0.f};

    // prefetch kt=0
    short8 bpre[2];
    bpre[0] = *(const short8*)bsrc[0];
    bpre[1] = *(const short8*)bsrc[1];
    float4 apre[4];
    {
        const int e0 = q * 8;
        apre[0] = *(const float4*)(arow0 + e0);
        apre[1] = *(const float4*)(arow0 + e0 + 4);
        apre[2] = *(const float4*)(arow1 + e0);
        apre[3] = *(const float4*)(arow1 + e0 + 4);
    }

#pragma unroll 1
    for (int kt = 0; kt < 10; ++kt) {
        const int buf = kt & 1;
        *(short8*)&Bs[buf][w][lane * 8] = bpre[0];
        *(short8*)&Bs[buf][w + 8][lane * 8] = bpre[1];
        __syncthreads();

        const short8 af0 = pack8(apre[0], apre[1]);
        const short8 af1 = pack8(apre[2], apre[3]);

        if (kt < 9) {
            const int e0n = (kt + 1) * 32 + q * 8;
            if (kt + 1 < 9) {
                apre[0] = *(const float4*)(arow0 + e0n);
                apre[1] = *(const float4*)(arow0 + e0n + 4);
                apre[2] = *(const float4*)(arow1 + e0n);
                apre[3] = *(const float4*)(arow1 + e0n + 4);
            } else {  // kt+1 == 9: K tail [288,320), guard e<300 (B is zero there)
                float va[8], vb[8];
#pragma unroll
                for (int j = 0; j < 8; ++j) {
                    const int e = e0n + j;
                    va[j] = (e < E_) ? arow0[e] : 0.0f;
                    vb[j] = (e < E_) ? arow1[e] : 0.0f;
                }
                apre[0] = (float4){va[0], va[1], va[2], va[3]};
                apre[1] = (float4){va[4], va[5], va[6], va[7]};
                apre[2] = (float4){vb[0], vb[1], vb[2], vb[3]};
                apre[3] = (float4){vb[4], vb[5], vb[6], vb[7]};
            }
            bpre[0] = *(const short8*)(bsrc[0] + (kt + 1) * 512);
            bpre[1] = *(const short8*)(bsrc[1] + (kt + 1) * 512);
        }

#pragma unroll
        for (int f = 0; f < 16; ++f) {
            const int dir = f >> 3, jj = (f >> 2) & 1, gt = f & 3;
            const short8 bf = *(const short8*)&Bs[buf][f][lane * 8];
            acc[jj][gt][0][dir] = __builtin_amdgcn_mfma_f32_16x16x32_bf16(af0, bf, acc[jj][gt][0][dir], 0, 0, 0);
            acc[jj][gt][1][dir] = __builtin_amdgcn_mfma_f32_16x16x32_bf16(af1, bf, acc[jj][gt][1][dir], 0, 0, 0);
        }
    }

    // epilogue: bias, scale x64, pack {i,f,g,o} -> one dword per (v, j)
    float bias[2][2][4];  // [dir][jj][gt]
#pragma unroll
    for (int d = 0; d < 2; ++d)
#pragma unroll
        for (int jj = 0; jj < 2; ++jj)
#pragma unroll
            for (int gt = 0; gt < 4; ++gt) {
                const int g = gt * 256 + (jt0 + jj) * 16 + n;
                bias[d][jj][gt] = d ? (b_ih_b[g] + b_hh_b[g]) : (b_ih_f[g] + b_hh_f[g]);
            }

#pragma unroll
    for (int d = 0; d < 2; ++d) {
        unsigned int* tgd = (unsigned int*)(tg8 + (size_t)d * 51200000);
#pragma unroll
        for (int jj = 0; jj < 2; ++jj) {
            const int dcol = (jt0 + jj) * 16 + n;  // dword index within row
#pragma unroll
            for (int rt = 0; rt < 2; ++rt) {
#pragma unroll
                for (int r = 0; r < 4; ++r) {
                    const int v = v0 + rt * 16 + q * 4 + r;
                    if (v < V_) {
                        const float x0 = (acc[jj][0][rt][d][r] + bias[d][jj][0]) * 64.0f;
                        const float x1 = (acc[jj][1][rt][d][r] + bias[d][jj][1]) * 64.0f;
                        const float x2 = (acc[jj][2][rt][d][r] + bias[d][jj][2]) * 64.0f;
                        const float x3 = (acc[jj][3][rt][d][r] + bias[d][jj][3]) * 64.0f;
                        tgd[(size_t)v * 256 + dcol] = pk_fp8(x0, x1) | (pk_fp8(x2, x3) << 16);
                    }
                }
            }
        }
    }
}

// ---------------------------------------------------------------------------
// Merged fp8 LSTM (round-6 verified — frozen this round).
// ---------------------------------------------------------------------------
__global__ __launch_bounds__(1024, 4) void lstm_fp8(const unsigned char* __restrict__ tg8,
                                                    const ull* __restrict__ wB8,
                                                    const int* __restrict__ words,
                                                    const ull* __restrict__ linB8,
                                                    unsigned short* __restrict__ emf,
                                                    unsigned short* __restrict__ emb) {
    __shared__ __align__(16) unsigned char hbuf[2][16][264];
    const int tid = threadIdx.x;
    const int wv = tid >> 6;
    const int lane = tid & 63;
    const int n = lane & 15;
    const int q = lane >> 4;
    const int dir = blockIdx.x >> 4;
    const int b0 = (blockIdx.x & 15) * 16;

    for (int i = tid; i < 2 * 16 * 264; i += 1024) (&hbuf[0][0][0])[i] = 0;
    __syncthreads();

    float cst[4] = {0.f, 0.f, 0.f, 0.f};

    const int l0 = dir ? (L_ - 1) : 0;
    const int dl = dir ? -1 : 1;

    ull wfrag[32];
    {
        const ull* wbase = wB8 + (size_t)dir * 32768 + (size_t)wv * 2048 + lane;
#pragma unroll
        for (int i = 0; i < 32; ++i) wfrag[i] = wbase[i * 64];
    }

    const unsigned char* tgd = tg8 + (size_t)dir * 51200000;
    const unsigned int laneoff = wv * 64 + n * 4;
    unsigned short* emx = dir ? emb : emf;
    const ull* lfrag = linB8 + (size_t)(dir * 2 + wv) * 512 + lane;
    const int t_em = wv * 16 + n;

    const float kSig = -1.4426950408889634f / 64.0f;
    const float kTanh = 2.8853900817779268f / 64.0f;

    unsigned int tgr[4];
    int4 wnxt;
    {
        const int4 w04 = *(const int4*)&words[l0 * B_ + b0 + q * 4];
        tgr[0] = *(const unsigned int*)(tgd + (((unsigned)w04.x << 10) + laneoff));
        tgr[1] = *(const unsigned int*)(tgd + (((unsigned)w04.y << 10) + laneoff));
        tgr[2] = *(const unsigned int*)(tgd + (((unsigned)w04.z << 10) + laneoff));
        tgr[3] = *(const unsigned int*)(tgd + (((unsigned)w04.w << 10) + laneoff));
        wnxt = *(const int4*)&words[(l0 + dl) * B_ + b0 + q * 4];
    }

    int p = 0;
    for (int step = 0; step < L_; ++step) {
        const int l = l0 + dl * step;
        f32x4 acc[4];
#pragma unroll
        for (int r = 0; r < 4; ++r) {
            f32x2 p0 = pk_f32<false>(tgr[r]);
            f32x2 p1 = pk_f32<true>(tgr[r]);
            acc[0][r] = p0.x; acc[1][r] = p0.y; acc[2][r] = p1.x; acc[3][r] = p1.y;
        }

        if (step + 1 < L_) {
            tgr[0] = *(const unsigned int*)(tgd + (((unsigned)wnxt.x << 10) + laneoff));
            tgr[1] = *(const unsigned int*)(tgd + (((unsigned)wnxt.y << 10) + laneoff));
            tgr[2] = *(const unsigned int*)(tgd + (((unsigned)wnxt.z << 10) + laneoff));
            tgr[3] = *(const unsigned int*)(tgd + (((unsigned)wnxt.w << 10) + laneoff));
        }
        int4 wtmp = {0, 0, 0, 0};
        if (step + 2 < L_) {
            wtmp = *(const int4*)&words[(l + 2 * dl) * B_ + b0 + q * 4];
        }

#pragma unroll
        for (int kt = 0; kt < 8; ++kt) {
            const ull af = *(const ull*)&hbuf[p][n][kt * 32 + q * 8];
#pragma unroll
            for (int gt = 0; gt < 4; ++gt)
                acc[gt] = __builtin_amdgcn_mfma_f32_16x16x32_fp8_fp8(
                    (long long)af, (long long)wfrag[kt * 4 + gt], acc[gt], 0, 0, 0);
        }

        float hv[4];
#pragma unroll
        for (int r = 0; r < 4; ++r) {
            const float ig = RCP(1.0f + EXP2(acc[0][r] * kSig));
            const float fg = RCP(1.0f + EXP2(acc[1][r] * kSig));
            const float gg = fmaf(-2.0f, RCP(EXP2(acc[2][r] * kTanh) + 1.0f), 1.0f);
            const float og = RCP(1.0f + EXP2(acc[3][r] * kSig));
            const float cn = fmaf(fg, cst[r], ig * gg);
            cst[r] = cn;
            hv[r] = og * tanh_(cn);
        }
        {
            const unsigned int p01 = pk_fp8(hv[0] * 8.0f, hv[1] * 8.0f);
            const unsigned int p23 = pk_fp8(hv[2] * 8.0f, hv[3] * 8.0f);
            hbuf[p ^ 1][q * 4 + 0][wv * 16 + n] = (unsigned char)(p01 & 0xff);
            hbuf[p ^ 1][q * 4 + 1][wv * 16 + n] = (unsigned char)(p01 >> 8);
            hbuf[p ^ 1][q * 4 + 2][wv * 16 + n] = (unsigned char)(p23 & 0xff);
            hbuf[p ^ 1][q * 4 + 3][wv * 16 + n] = (unsigned char)(p23 >> 8);
        }
        __syncthreads();

        if (wv < 2) {
            f32x4 eacc = (f32x4){0.f, 0.f, 0.f, 0.f};
#pragma unroll
            for (int kt = 0; kt < 8; ++kt) {
                const ull af = *(const ull*)&hbuf[p ^ 1][n][kt * 32 + q * 8];
                eacc = __builtin_amdgcn_mfma_f32_16x16x32_fp8_fp8(
                    (long long)af, (long long)lfrag[kt * 64], eacc, 0, 0, 0);
            }
            if (t_em < T_) {
                const size_t embase = ((size_t)l * B_ + b0) * T_ + t_em + (size_t)q * 4 * T_;
#pragma unroll
                for (int r = 0; r < 4; ++r)
                    emx[embase + r * T_] = (unsigned short)f2bf(eacc[r] * (1.0f / 256.0f));
            }
        }

        wnxt = wtmp;
        p ^= 1;
    }
}

// ---------------------------------------------------------------------------
// CRF: one wave per sequence (verified — frozen).
// ---------------------------------------------------------------------------
__global__ __launch_bounds__(64) void crf_kernel(const unsigned short* __restrict__ emf,
                                                 const unsigned short* __restrict__ emb,
                                                 const int* __restrict__ tags,
                                                 const int* __restrict__ mask,
                                                 const float* __restrict__ start_trans,
                                                 const float* __restrict__ end_trans,
                                                 const float* __restrict__ trans,
                                                 const float* __restrict__ lin_b,
                                                 float* __restrict__ llh) {
    const int b = blockIdx.x;
    const int t = threadIdx.x;
    __shared__ float tr[T_ * T_];
    __shared__ float lb[T_];
    for (int i = t; i < T_ * T_; i += 64) tr[i] = trans[i];
    if (t < T_) lb[t] = lin_b[t];
    __syncthreads();

    const int tc = (t < T_) ? t : (T_ - 1);
    const float lbc = lb[tc];
    float trc[T_];
#pragma unroll
    for (int s = 0; s < T_; ++s) trc[s] = tr[s * T_ + tc];

    float part = 0.0f;
    int msum = 0;
    for (int l = t; l < L_; l += 64) {
        const int idx = l * B_ + b;
        const int m = mask[idx];
        msum += m;
        const int tl = tags[idx];
        const float emt = bf2f(emf[(size_t)idx * T_ + tl]) + bf2f(emb[(size_t)idx * T_ + tl]) + lb[tl];
        if (l == 0) {
            part += start_trans[tl] + emt;
        } else {
            const int tp = tags[(l - 1) * B_ + b];
            part += m ? (tr[tp * T_ + tl] + emt) : 0.0f;
        }
    }
    for (int o = 32; o; o >>= 1) {
        part += __shfl_down(part, o);
        msum += __shfl_down(msum, o);
    }
    const int len = __shfl(msum, 0);

    float alpha = start_trans[tc] + bf2f(emf[(size_t)b * T_ + tc]) + bf2f(emb[(size_t)b * T_ + tc]) + lbc;
    float env = 0.0f;
    if (len > 1) {
        const size_t i1 = ((size_t)B_ + b) * T_ + tc;
        env = bf2f(emf[i1]) + bf2f(emb[i1]) + lbc;
    }
    for (int l = 1; l < len; ++l) {
        const float cur = env;
        if (l + 1 < len) {
            const size_t ix = ((size_t)(l + 1) * B_ + b) * T_ + tc;
            env = bf2f(emf[ix]) + bf2f(emb[ix]) + lbc;
        }
        float mx = -1e30f;
#pragma unroll
        for (int s = 0; s < T_; ++s) {
            const float as = __shfl(alpha, s);
            mx = fmaxf(mx, as + trc[s]);
        }
        float sm = 0.0f;
#pragma unroll
        for (int s = 0; s < T_; ++s) {
            const float as = __shfl(alpha, s);
            sm += __expf(as + trc[s] - mx);
        }
        alpha = mx + __logf(sm) + cur;
    }
    float val = (t < T_) ? (alpha + end_trans[t]) : -1e30f;
    float mx = val;
    for (int o = 32; o; o >>= 1) mx = fmaxf(mx, __shfl_down(mx, o));
    const float mx_all = __shfl(mx, 0);
    float sm = __expf(val - mx_all);
    for (int o = 32; o; o >>= 1) sm += __shfl_down(sm, o);

    if (t == 0) {
        const float score = part + end_trans[tags[(len - 1) * B_ + b]];
        const float logZ = mx_all + __logf(sm);
        llh[b] = score - logZ;
    }
}

__global__ __launch_bounds__(256) void final_reduce(const float* __restrict__ llh,
                                                    float* __restrict__ out) {
    const int t = threadIdx.x;
    float v = llh[t];
    for (int o = 32; o; o >>= 1) v += __shfl_down(v, o);
    __shared__ float wsum[4];
    if ((t & 63) == 0) wsum[t >> 6] = v;
    __syncthreads();
    if (t == 0) out[0] = -(wsum[0] + wsum[1] + wsum[2] + wsum[3]);
}

// ---------------------------------------------------------------------------
extern "C" void kernel_launch(void* const* d_in, const int* in_sizes, int n_in,
                              void* d_out, int out_size, void* d_ws, size_t ws_size,
                              hipStream_t stream) {
    const int* words = (const int*)d_in[0];
    const int* tags = (const int*)d_in[1];
    const int* mask = (const int*)d_in[2];
    const float* table = (const float*)d_in[3];
    const float* w_ih_f = (const float*)d_in[4];
    const float* w_hh_f = (const float*)d_in[5];
    const float* b_ih_f = (const float*)d_in[6];
    const float* b_hh_f = (const float*)d_in[7];
    const float* w_ih_b = (const float*)d_in[8];
    const float* w_hh_b = (const float*)d_in[9];
    const float* b_ih_b = (const float*)d_in[10];
    const float* b_hh_b = (const float*)d_in[11];
    const float* lin_w = (const float*)d_in[12];
    const float* lin_b = (const float*)d_in[13];
    const float* start_trans = (const float*)d_in[14];
    const float* end_trans = (const float*)d_in[15];
    const float* trans = (const float*)d_in[16];

    char* ws = (char*)d_ws;
    unsigned char* tg8 = (unsigned char*)ws;                    // 102,400,000 (2 dirs)
    unsigned char* wB8 = (unsigned char*)(ws + 102400000);      //     524,288
    unsigned char* linB8 = (unsigned char*)(ws + 102924288);    //      16,384
    unsigned short* emf = (unsigned short*)(ws + 102940672);    //   2,228,224
    unsigned short* emb = (unsigned short*)(ws + 105168896);    //   2,228,224
    float* llh = (float*)(ws + 107397120);                      //       1,024
    // total: 107,398,144 B (verified footprint)
    // wBihF/wBihB (655,360 B each) alias emf/emb during the GEMM phase only.
    unsigned short* wBihF = emf;
    unsigned short* wBihB = emb;

    prep_all<<<2112, 256, 0, stream>>>(w_hh_f, w_hh_b, lin_w, wB8, linB8);
    prep_bih<<<2560, 256, 0, stream>>>(w_ih_f, w_ih_b, wBihF, wBihB);

    tg_gemm<<<dim3(196, 8), 512, 0, stream>>>(table, wBihF, wBihB,
                                              b_ih_f, b_hh_f, b_ih_b, b_hh_b, tg8);

    lstm_fp8<<<32, 1024, 0, stream>>>(tg8, (const ull*)wB8, words, (const ull*)linB8, emf, emb);

    crf_kernel<<<256, 64, 0, stream>>>(emf, emb, tags, mask, start_trans, end_trans, trans, lin_b, llh);
    final_reduce<<<1, 256, 0, stream>>>(llh, (float*)d_out);
}